// Round 31
// baseline (79.482 us; speedup 1.0000x reference)
//
#include <hip/hip_runtime.h>
#include <hip/hip_bf16.h>

#define BN 2048      // B*N
#define NSEQ 512
#define D 256
#define H 128
#define R 16
#define AC 5
#define ROWG 4
#define IG 4         // valid-i rows per pair block
#define JSPLIT 8     // j-slices per batch
#define JCHUNK 32

using bf16 = __hip_bfloat16;

__device__ __forceinline__ float fast_silu(float t) {
    const float e = __expf(-t);
    return t * __builtin_amdgcn_rcpf(1.0f + e);
}
__device__ __forceinline__ float bf2f(unsigned short u) {
    return __uint_as_float(((unsigned)u) << 16);
}

// ---------------- Kernel 0: per-batch valid compaction (list serves as both i-list and j-list) ----------------
__global__ __launch_bounds__(256) void batch_kernel(
    const int* __restrict__ pad, int* __restrict__ jlist_g, int* __restrict__ M_g)
{
    const int b = blockIdx.x;
    const int tid = threadIdx.x;
    __shared__ int s_wcnt[8];
    __shared__ int s_wbase[8];
    const int wv = tid >> 6, lane = tid & 63;
    unsigned long long bm[2];
    #pragma unroll
    for (int cc = 0; cc < 2; ++cc) {
        const int j = cc * 256 + tid;
        const int ok = (pad[b * NSEQ + j] == 0);
        bm[cc] = __ballot(ok);
        if (lane == 0) s_wcnt[cc * 4 + wv] = __popcll(bm[cc]);
    }
    __syncthreads();
    if (tid == 0) {
        int acc = 0;
        #pragma unroll
        for (int q = 0; q < 8; ++q) { s_wbase[q] = acc; acc += s_wcnt[q]; }
        M_g[b] = acc;
    }
    __syncthreads();
    #pragma unroll
    for (int cc = 0; cc < 2; ++cc) {
        const int j = cc * 256 + tid;
        if (pad[b * NSEQ + j] == 0) {
            const int pos = s_wbase[cc * 4 + wv]
                          + __popcll(bm[cc] & ((1ull << lane) - 1ull));
            jlist_g[b * NSEQ + pos] = j;
        }
    }
}

// ---------------- Kernel 1: atom head + pj + pib, ROWG=4 rows/block (passes, unchanged) ----------------
__global__ __launch_bounds__(256) void row_kernel(
    const float* __restrict__ trunk, const int* __restrict__ pad,
    const float* __restrict__ ln_g, const float* __restrict__ ln_b,
    const float* __restrict__ w_a1, const float* __restrict__ b_a1,
    const float* __restrict__ w_a2, const float* __restrict__ b_a2,
    const float* __restrict__ w_pi, const float* __restrict__ w_pj,
    const float* __restrict__ b_p1,
    float* __restrict__ out_atom, float* __restrict__ pj_o,
    unsigned short* __restrict__ pib_o)
{
    const int row0 = blockIdx.x * ROWG;
    const int tid = threadIdx.x;
    const int wv = tid >> 6, lane = tid & 63;
    __shared__ __align__(16) float x_t[D][ROWG];
    __shared__ __align__(16) float xn_t[D][ROWG];
    __shared__ float y[ROWG][D];
    __shared__ float mu_s[ROWG], rs_s[ROWG];

    #pragma unroll
    for (int g = 0; g < ROWG; ++g)
        x_t[tid][g] = trunk[(size_t)(row0 + g) * D + tid];
    __syncthreads();

    {
        const int g = wv;
        float s = 0.0f, ss = 0.0f;
        #pragma unroll
        for (int e = lane; e < D; e += 64) {
            const float v = x_t[e][g];
            s += v; ss += v * v;
        }
        #pragma unroll
        for (int off = 32; off; off >>= 1) {
            s  += __shfl_xor(s, off);
            ss += __shfl_xor(ss, off);
        }
        if (lane == 0) {
            const float mu  = s * (1.0f / D);
            const float var = ss * (1.0f / D) - mu * mu;
            mu_s[g] = mu;
            rs_s[g] = rsqrtf(var + 1e-5f);
        }
    }
    __syncthreads();
    {
        const float lg = ln_g[tid], lb = ln_b[tid];
        #pragma unroll
        for (int g = 0; g < ROWG; ++g)
            xn_t[tid][g] = (x_t[tid][g] - mu_s[g]) * rs_s[g] * lg + lb;
    }
    __syncthreads();

    {
        float acc0 = b_a1[tid], acc1 = acc0, acc2 = acc0, acc3 = acc0;
        for (int d = 0; d < D; ++d) {
            const float w = w_a1[d * D + tid];
            const float4 xv = *(const float4*)xn_t[d];
            acc0 = fmaf(xv.x, w, acc0);
            acc1 = fmaf(xv.y, w, acc1);
            acc2 = fmaf(xv.z, w, acc2);
            acc3 = fmaf(xv.w, w, acc3);
        }
        y[0][tid] = acc0 / (1.0f + expf(-acc0));
        y[1][tid] = acc1 / (1.0f + expf(-acc1));
        y[2][tid] = acc2 / (1.0f + expf(-acc2));
        y[3][tid] = acc3 / (1.0f + expf(-acc3));
    }

    float p0 = 0.0f, p1 = 0.0f, p2 = 0.0f, p3 = 0.0f;
    if (tid < H) {
        for (int d = 0; d < D; ++d) {
            const float w = w_pi[d * H + tid];
            const float4 xv = *(const float4*)x_t[d];
            p0 = fmaf(xv.x, w, p0);
            p1 = fmaf(xv.y, w, p1);
            p2 = fmaf(xv.z, w, p2);
            p3 = fmaf(xv.w, w, p3);
        }
        const float bb = b_p1[tid];
        p0 += bb; p1 += bb; p2 += bb; p3 += bb;
    } else {
        const int h = tid - H;
        for (int d = 0; d < D; ++d) {
            const float w = w_pj[d * H + h];
            const float4 xv = *(const float4*)x_t[d];
            p0 = fmaf(xv.x, w, p0);
            p1 = fmaf(xv.y, w, p1);
            p2 = fmaf(xv.z, w, p2);
            p3 = fmaf(xv.w, w, p3);
        }
    }
    __syncthreads();
    if (tid < H) {
        const float pv[ROWG] = {p0, p1, p2, p3};
        #pragma unroll
        for (int g = 0; g < ROWG; ++g) {
            const bf16 pb = __float2bfloat16(pv[g]);
            pib_o[(size_t)(row0 + g) * H + tid] = *(const unsigned short*)&pb;
        }
    } else {
        const int h = tid - H;
        const float pv[ROWG] = {p0, p1, p2, p3};
        #pragma unroll
        for (int g = 0; g < ROWG; ++g)
            pj_o[(size_t)(row0 + g) * H + h] = pv[g];
    }

    if (tid < ROWG * AC) {
        const int g = tid / AC, c = tid % AC;
        float a = b_a2[c];
        for (int d = 0; d < D; ++d) a = fmaf(y[g][d], w_a2[d * AC + c], a);
        out_atom[(row0 + g) * AC + c] = (pad[row0 + g] != 0) ? 0.0f : a;
    }
}

// per-pair inner body (register state only)
__device__ __forceinline__ void pair_body(
    const float pvx, const float pvy,
    const float* __restrict__ rbf_row, const float4 dk,
    const float pibx, const float piby,
    const float* wprA, const float* wprB, const float2 wp22,
    float& cdx, float& cdy, float& cdz,
    float& sdx, float& sdy, float& sdz)
{
    float t0a = pibx + pvx, t0b = 0.0f;
    float t1a = piby + pvy, t1b = 0.0f;
    #pragma unroll
    for (int r = 0; r < R; r += 2) {
        const float qa = rbf_row[r];
        const float qb = rbf_row[r + 1];
        t0a = fmaf(qa, wprA[r],     t0a);
        t0b = fmaf(qb, wprA[r + 1], t0b);
        t1a = fmaf(qa, wprB[r],     t1a);
        t1b = fmaf(qb, wprB[r + 1], t1b);
    }
    const float u0 = fast_silu(t0a + t0b);
    const float u1 = fast_silu(t1a + t1b);
    const float part = u0 * wp22.x + u1 * wp22.y;
    cdx = fmaf(part, dk.x, cdx);
    cdy = fmaf(part, dk.y, cdy);
    cdz = fmaf(part, dk.z, cdz);
    sdx += dk.x; sdy += dk.y; sdz += dk.z;
}

// ---------------- Kernel 2: pair head — IG=4 i-rows share each pv load; JSPLIT=8 ----------------
__global__ __launch_bounds__(256) void pair_kernel(
    const float* __restrict__ coords,
    const float* __restrict__ w_pr, const float* __restrict__ w_p2,
    const float* __restrict__ b_p2,
    const float* __restrict__ pj_i, const unsigned short* __restrict__ pib_i,
    const int* __restrict__ jlist_g, const int* __restrict__ M_g,
    float* __restrict__ cd_part)   // [BN][JSPLIT][3]
{
    const int part = blockIdx.x & (JSPLIT - 1);
    const int tmp  = blockIdx.x >> 3;
    const int gi   = tmp & ((NSEQ / IG) - 1);   // 0..127
    const int b    = tmp >> 7;
    const int tid  = threadIdx.x;
    const int wv = tid >> 6, lane = tid & 63;

    const int M  = M_g[b];
    const int i0 = gi * IG;
    if (i0 >= M) return;                 // block-uniform
    const int nI = min(IG, M - i0);

    const int Mq  = (M + JSPLIT - 1) >> 3;
    const int kLo = part * Mq;
    const int kHi = min(M, kLo + Mq);

    __shared__ int   s_irow[IG];
    __shared__ float s_ci[IG][3];
    __shared__ __align__(16) float s_rbf[IG][JCHUNK][20];  // 10 KB
    __shared__ __align__(16) float4 s_d4[IG][JCHUNK];      // 2 KB
    __shared__ int   s_jl[JCHUNK];
    __shared__ float s_red[4][IG][3];

    if (tid < IG) {
        if (tid < nI) {
            const int il  = jlist_g[b * NSEQ + i0 + tid];
            const int row = b * NSEQ + il;
            s_irow[tid] = row;
            s_ci[tid][0] = coords[(size_t)row * 3 + 0];
            s_ci[tid][1] = coords[(size_t)row * 3 + 1];
            s_ci[tid][2] = coords[(size_t)row * 3 + 2];
        } else {
            s_irow[tid] = b * NSEQ;      // dummy, in-range
            s_ci[tid][0] = 0.0f; s_ci[tid][1] = 0.0f; s_ci[tid][2] = 0.0f;
        }
    }
    __syncthreads();

    if (kLo >= kHi) {                    // empty j-slice: zero this part
        if (tid < nI * 3) {
            const int ii = tid / 3, c = tid % 3;
            cd_part[((size_t)s_irow[ii] * JSPLIT + part) * 3 + c] = 0.0f;
        }
        return;
    }

    float wprA[R], wprB[R];
    #pragma unroll
    for (int r = 0; r < R; ++r) {
        const float2 wv2 = ((const float2*)(w_pr + r * H))[lane];
        wprA[r] = wv2.x;
        wprB[r] = wv2.y;
    }
    float pibx[IG], piby[IG];
    #pragma unroll
    for (int ii = 0; ii < IG; ++ii) {
        const ushort2 u = ((const ushort2*)(pib_i + (size_t)s_irow[ii] * H))[lane];
        pibx[ii] = bf2f(u.x);
        piby[ii] = bf2f(u.y);
    }
    const float2 wp22 = ((const float2*)w_p2)[lane];
    const float bp2 = b_p2[0];

    float cdx[IG] = {0.f, 0.f, 0.f, 0.f};
    float cdy[IG] = {0.f, 0.f, 0.f, 0.f};
    float cdz[IG] = {0.f, 0.f, 0.f, 0.f};
    float sdx[IG] = {0.f, 0.f, 0.f, 0.f};
    float sdy[IG] = {0.f, 0.f, 0.f, 0.f};
    float sdz[IG] = {0.f, 0.f, 0.f, 0.f};
    const float* pjb = pj_i + (size_t)b * NSEQ * H;
    const float gamma = 14.0625f;  // (15/4)^2

    for (int c0 = kLo; c0 < kHi; c0 += JCHUNK) {
        const int cn = min(JCHUNK, kHi - c0);
        __syncthreads();
        // 2-D staging: thread (ii = tid>>5, kk = tid&31) stages one (i, j) combo
        {
            const int kk = tid & (JCHUNK - 1);
            const int ii = tid >> 5;
            if (ii < IG && kk < cn) {
                const int j = jlist_g[b * NSEQ + c0 + kk];
                if (ii == 0) s_jl[kk] = j;
                const float* cj = coords + (size_t)(b * NSEQ + j) * 3;
                const float dx = s_ci[ii][0] - cj[0];
                const float dy = s_ci[ii][1] - cj[1];
                const float dz = s_ci[ii][2] - cj[2];
                const float sq = dx * dx + dy * dy + dz * dz;
                const float dist = sqrtf(fmaxf(sq, 1e-12f));
                s_d4[ii][kk] = make_float4(dx, dy, dz, 0.0f);
                #pragma unroll
                for (int c = 0; c < 4; ++c) {
                    float4 q;
                    const float t0 = dist - (float)(4.0 * (4 * c + 0) / 15.0);
                    const float t1 = dist - (float)(4.0 * (4 * c + 1) / 15.0);
                    const float t2 = dist - (float)(4.0 * (4 * c + 2) / 15.0);
                    const float t3 = dist - (float)(4.0 * (4 * c + 3) / 15.0);
                    q.x = __expf(-gamma * t0 * t0);
                    q.y = __expf(-gamma * t1 * t1);
                    q.z = __expf(-gamma * t2 * t2);
                    q.w = __expf(-gamma * t3 * t3);
                    *(float4*)(&s_rbf[ii][kk][4 * c]) = q;
                }
            }
        }
        __syncthreads();
        // main loop: one pv load feeds IG pair bodies
        for (int k = wv; k < cn; k += 4) {
            const int j = s_jl[k];
            const float2 pv = ((const float2*)(pjb + (size_t)j * H))[lane];
            #pragma unroll
            for (int ii = 0; ii < IG; ++ii) {
                pair_body(pv.x, pv.y, s_rbf[ii][k], s_d4[ii][k],
                          pibx[ii], piby[ii], wprA, wprB, wp22,
                          cdx[ii], cdy[ii], cdz[ii], sdx[ii], sdy[ii], sdz[ii]);
            }
        }
    }
    // per-i butterfly (once per block), sd is wave-uniform (no reduce needed)
    #pragma unroll
    for (int ii = 0; ii < IG; ++ii) {
        #pragma unroll
        for (int off = 32; off; off >>= 1) {
            cdx[ii] += __shfl_xor(cdx[ii], off);
            cdy[ii] += __shfl_xor(cdy[ii], off);
            cdz[ii] += __shfl_xor(cdz[ii], off);
        }
    }
    if (lane == 0) {
        #pragma unroll
        for (int ii = 0; ii < IG; ++ii) {
            s_red[wv][ii][0] = cdx[ii] + bp2 * sdx[ii];
            s_red[wv][ii][1] = cdy[ii] + bp2 * sdy[ii];
            s_red[wv][ii][2] = cdz[ii] + bp2 * sdz[ii];
        }
    }
    __syncthreads();
    if (tid < nI * 3) {
        const int ii = tid / 3, c = tid % 3;
        cd_part[((size_t)s_irow[ii] * JSPLIT + part) * 3 + c] =
            s_red[0][ii][c] + s_red[1][ii][c] + s_red[2][ii][c] + s_red[3][ii][c];
    }
}

// ---------------- Kernel 3: proper jax finalize (sums JSPLIT parts; pad-gated reads) ----------------
__global__ __launch_bounds__(256) void finalize_kernel(
    const float* __restrict__ cd_part, const int* __restrict__ pad,
    float* __restrict__ out_coord)
{
    const int b = blockIdx.x;
    const int tid = threadIdx.x;
    __shared__ float r1[256], r2[256], r3[256], r4[256];
    float sx = 0.0f, sy = 0.0f, sz = 0.0f, cnt = 0.0f;
    for (int ii = tid; ii < NSEQ; ii += 256) {
        const int row = b * NSEQ + ii;
        if (pad[row] == 0) {
            float cx = 0.0f, cy = 0.0f, cz = 0.0f;
            #pragma unroll
            for (int q = 0; q < JSPLIT; ++q) {
                cx += cd_part[((size_t)row * JSPLIT + q) * 3 + 0];
                cy += cd_part[((size_t)row * JSPLIT + q) * 3 + 1];
                cz += cd_part[((size_t)row * JSPLIT + q) * 3 + 2];
            }
            sx += cx; sy += cy; sz += cz;
            cnt += 1.0f;
        }
    }
    r1[tid] = sx; r2[tid] = sy; r3[tid] = sz; r4[tid] = cnt;
    __syncthreads();
    for (int s = 128; s > 0; s >>= 1) {
        if (tid < s) {
            r1[tid] += r1[tid + s]; r2[tid] += r2[tid + s];
            r3[tid] += r3[tid + s]; r4[tid] += r4[tid + s];
        }
        __syncthreads();
    }
    const float denom = fmaxf(r4[0], 1.0f);
    const float inv_d = 1.0f / denom;
    const float mx = r1[0] * inv_d * inv_d;
    const float my = r2[0] * inv_d * inv_d;
    const float mz = r3[0] * inv_d * inv_d;
    for (int ii = tid; ii < NSEQ; ii += 256) {
        const int row = b * NSEQ + ii;
        if (pad[row] == 0) {
            float cx = 0.0f, cy = 0.0f, cz = 0.0f;
            #pragma unroll
            for (int q = 0; q < JSPLIT; ++q) {
                cx += cd_part[((size_t)row * JSPLIT + q) * 3 + 0];
                cy += cd_part[((size_t)row * JSPLIT + q) * 3 + 1];
                cz += cd_part[((size_t)row * JSPLIT + q) * 3 + 2];
            }
            out_coord[row * 3 + 0] = cx * inv_d - mx;
            out_coord[row * 3 + 1] = cy * inv_d - my;
            out_coord[row * 3 + 2] = cz * inv_d - mz;
        } else {
            out_coord[row * 3 + 0] = 0.0f;
            out_coord[row * 3 + 1] = 0.0f;
            out_coord[row * 3 + 2] = 0.0f;
        }
    }
}

extern "C" void kernel_launch(void* const* d_in, const int* in_sizes, int n_in,
                              void* d_out, int out_size, void* d_ws, size_t ws_size,
                              hipStream_t stream) {
    const float* trunk  = (const float*)d_in[0];
    const float* coords = (const float*)d_in[1];
    const int*   pad    = (const int*)d_in[2];
    const float* ln_g   = (const float*)d_in[3];
    const float* ln_b   = (const float*)d_in[4];
    const float* w_a1   = (const float*)d_in[5];
    const float* b_a1   = (const float*)d_in[6];
    const float* w_a2   = (const float*)d_in[7];
    const float* b_a2   = (const float*)d_in[8];
    const float* w_pi   = (const float*)d_in[9];
    const float* w_pj   = (const float*)d_in[10];
    const float* w_pr   = (const float*)d_in[11];
    const float* b_p1   = (const float*)d_in[12];
    const float* w_p2   = (const float*)d_in[13];
    const float* b_p2   = (const float*)d_in[14];

    float* out_atom  = (float*)d_out;                 // f32 [0:10240]
    float* out_coord = out_atom + (size_t)BN * AC;    // f32 [10240:16384]

    // ws: jlist[4*512] M[16] | cd_part[BN*JSPLIT*3] | pj f32[BN*H] | pib bf16[BN*H]
    int*   jlist_g = (int*)d_ws;
    int*   M_g     = jlist_g + 4 * NSEQ;
    float* cd_part = (float*)(M_g + 16);
    float* pj_buf  = cd_part + (size_t)BN * JSPLIT * 3;
    unsigned short* pib_buf = (unsigned short*)(pj_buf + (size_t)BN * H);

    batch_kernel<<<4, 256, 0, stream>>>(pad, jlist_g, M_g);
    row_kernel<<<BN / ROWG, 256, 0, stream>>>(trunk, pad, ln_g, ln_b, w_a1, b_a1,
                                              w_a2, b_a2, w_pi, w_pj, b_p1,
                                              out_atom, pj_buf, pib_buf);
    pair_kernel<<<4 * (NSEQ / IG) * JSPLIT, 256, 0, stream>>>(
        coords, w_pr, w_p2, b_p2, pj_buf, pib_buf, jlist_g, M_g, cd_part);
    finalize_kernel<<<4, 256, 0, stream>>>(cd_part, pad, out_coord);
}

// Round 32
// 76.203 us; speedup vs baseline: 1.0430x; 1.0430x over previous
//
#include <hip/hip_runtime.h>
#include <hip/hip_bf16.h>

#define BN 2048      // B*N
#define NSEQ 512
#define D 256
#define H 128
#define R 16
#define AC 5
#define ROWG 4
#define IG 2         // valid-i rows per pair block
#define JSPLIT 4     // j-slices per batch
#define JCHUNK 64

using bf16 = __hip_bfloat16;

__device__ __forceinline__ float fast_silu(float t) {
    const float e = __expf(-t);
    return t * __builtin_amdgcn_rcpf(1.0f + e);
}
__device__ __forceinline__ float bf2f(unsigned short u) {
    return __uint_as_float(((unsigned)u) << 16);
}

// ---------------- Kernel 0: per-batch valid compaction ----------------
__global__ __launch_bounds__(256) void batch_kernel(
    const int* __restrict__ pad, int* __restrict__ jlist_g, int* __restrict__ M_g)
{
    const int b = blockIdx.x;
    const int tid = threadIdx.x;
    __shared__ int s_wcnt[8];
    __shared__ int s_wbase[8];
    const int wv = tid >> 6, lane = tid & 63;
    unsigned long long bm[2];
    #pragma unroll
    for (int cc = 0; cc < 2; ++cc) {
        const int j = cc * 256 + tid;
        const int ok = (pad[b * NSEQ + j] == 0);
        bm[cc] = __ballot(ok);
        if (lane == 0) s_wcnt[cc * 4 + wv] = __popcll(bm[cc]);
    }
    __syncthreads();
    if (tid == 0) {
        int acc = 0;
        #pragma unroll
        for (int q = 0; q < 8; ++q) { s_wbase[q] = acc; acc += s_wcnt[q]; }
        M_g[b] = acc;
    }
    __syncthreads();
    #pragma unroll
    for (int cc = 0; cc < 2; ++cc) {
        const int j = cc * 256 + tid;
        if (pad[b * NSEQ + j] == 0) {
            const int pos = s_wbase[cc * 4 + wv]
                          + __popcll(bm[cc] & ((1ull << lane) - 1ull));
            jlist_g[b * NSEQ + pos] = j;
        }
    }
}

// ---------------- Kernel 1: atom head + pj + pib, ROWG=4 (passes, unchanged) ----------------
__global__ __launch_bounds__(256) void row_kernel(
    const float* __restrict__ trunk, const int* __restrict__ pad,
    const float* __restrict__ ln_g, const float* __restrict__ ln_b,
    const float* __restrict__ w_a1, const float* __restrict__ b_a1,
    const float* __restrict__ w_a2, const float* __restrict__ b_a2,
    const float* __restrict__ w_pi, const float* __restrict__ w_pj,
    const float* __restrict__ b_p1,
    float* __restrict__ out_atom, float* __restrict__ pj_o,
    unsigned short* __restrict__ pib_o)
{
    const int row0 = blockIdx.x * ROWG;
    const int tid = threadIdx.x;
    const int wv = tid >> 6, lane = tid & 63;
    __shared__ __align__(16) float x_t[D][ROWG];
    __shared__ __align__(16) float xn_t[D][ROWG];
    __shared__ float y[ROWG][D];
    __shared__ float mu_s[ROWG], rs_s[ROWG];

    #pragma unroll
    for (int g = 0; g < ROWG; ++g)
        x_t[tid][g] = trunk[(size_t)(row0 + g) * D + tid];
    __syncthreads();

    {
        const int g = wv;
        float s = 0.0f, ss = 0.0f;
        #pragma unroll
        for (int e = lane; e < D; e += 64) {
            const float v = x_t[e][g];
            s += v; ss += v * v;
        }
        #pragma unroll
        for (int off = 32; off; off >>= 1) {
            s  += __shfl_xor(s, off);
            ss += __shfl_xor(ss, off);
        }
        if (lane == 0) {
            const float mu  = s * (1.0f / D);
            const float var = ss * (1.0f / D) - mu * mu;
            mu_s[g] = mu;
            rs_s[g] = rsqrtf(var + 1e-5f);
        }
    }
    __syncthreads();
    {
        const float lg = ln_g[tid], lb = ln_b[tid];
        #pragma unroll
        for (int g = 0; g < ROWG; ++g)
            xn_t[tid][g] = (x_t[tid][g] - mu_s[g]) * rs_s[g] * lg + lb;
    }
    __syncthreads();

    {
        float acc0 = b_a1[tid], acc1 = acc0, acc2 = acc0, acc3 = acc0;
        for (int d = 0; d < D; ++d) {
            const float w = w_a1[d * D + tid];
            const float4 xv = *(const float4*)xn_t[d];
            acc0 = fmaf(xv.x, w, acc0);
            acc1 = fmaf(xv.y, w, acc1);
            acc2 = fmaf(xv.z, w, acc2);
            acc3 = fmaf(xv.w, w, acc3);
        }
        y[0][tid] = acc0 / (1.0f + expf(-acc0));
        y[1][tid] = acc1 / (1.0f + expf(-acc1));
        y[2][tid] = acc2 / (1.0f + expf(-acc2));
        y[3][tid] = acc3 / (1.0f + expf(-acc3));
    }

    float p0 = 0.0f, p1 = 0.0f, p2 = 0.0f, p3 = 0.0f;
    if (tid < H) {
        for (int d = 0; d < D; ++d) {
            const float w = w_pi[d * H + tid];
            const float4 xv = *(const float4*)x_t[d];
            p0 = fmaf(xv.x, w, p0);
            p1 = fmaf(xv.y, w, p1);
            p2 = fmaf(xv.z, w, p2);
            p3 = fmaf(xv.w, w, p3);
        }
        const float bb = b_p1[tid];
        p0 += bb; p1 += bb; p2 += bb; p3 += bb;
    } else {
        const int h = tid - H;
        for (int d = 0; d < D; ++d) {
            const float w = w_pj[d * H + h];
            const float4 xv = *(const float4*)x_t[d];
            p0 = fmaf(xv.x, w, p0);
            p1 = fmaf(xv.y, w, p1);
            p2 = fmaf(xv.z, w, p2);
            p3 = fmaf(xv.w, w, p3);
        }
    }
    __syncthreads();
    if (tid < H) {
        const float pv[ROWG] = {p0, p1, p2, p3};
        #pragma unroll
        for (int g = 0; g < ROWG; ++g) {
            const bf16 pb = __float2bfloat16(pv[g]);
            pib_o[(size_t)(row0 + g) * H + tid] = *(const unsigned short*)&pb;
        }
    } else {
        const int h = tid - H;
        const float pv[ROWG] = {p0, p1, p2, p3};
        #pragma unroll
        for (int g = 0; g < ROWG; ++g)
            pj_o[(size_t)(row0 + g) * H + h] = pv[g];
    }

    if (tid < ROWG * AC) {
        const int g = tid / AC, c = tid % AC;
        float a = b_a2[c];
        for (int d = 0; d < D; ++d) a = fmaf(y[g][d], w_a2[d * AC + c], a);
        out_atom[(row0 + g) * AC + c] = (pad[row0 + g] != 0) ? 0.0f : a;
    }
}

// per-pair inner body (register state only)
__device__ __forceinline__ void pair_body(
    const float pvx, const float pvy,
    const float* __restrict__ rbf_row, const float4 dk,
    const float pibx, const float piby,
    const float* wprA, const float* wprB, const float2 wp22,
    float& cdx, float& cdy, float& cdz,
    float& sdx, float& sdy, float& sdz)
{
    float t0a = pibx + pvx, t0b = 0.0f;
    float t1a = piby + pvy, t1b = 0.0f;
    #pragma unroll
    for (int r = 0; r < R; r += 2) {
        const float qa = rbf_row[r];
        const float qb = rbf_row[r + 1];
        t0a = fmaf(qa, wprA[r],     t0a);
        t0b = fmaf(qb, wprA[r + 1], t0b);
        t1a = fmaf(qa, wprB[r],     t1a);
        t1b = fmaf(qb, wprB[r + 1], t1b);
    }
    const float u0 = fast_silu(t0a + t0b);
    const float u1 = fast_silu(t1a + t1b);
    const float part = u0 * wp22.x + u1 * wp22.y;
    cdx = fmaf(part, dk.x, cdx);
    cdy = fmaf(part, dk.y, cdy);
    cdz = fmaf(part, dk.z, cdz);
    sdx += dk.x; sdy += dk.y; sdz += dk.z;
}

// ---------------- Kernel 2: pair head — IG=2 share each pv load; JSPLIT=4; 2-wide prefetch ----------------
__global__ __launch_bounds__(256) void pair_kernel(
    const float* __restrict__ coords,
    const float* __restrict__ w_pr, const float* __restrict__ w_p2,
    const float* __restrict__ b_p2,
    const float* __restrict__ pj_i, const unsigned short* __restrict__ pib_i,
    const int* __restrict__ jlist_g, const int* __restrict__ M_g,
    float* __restrict__ cd_part)   // [BN][JSPLIT][3]
{
    const int part = blockIdx.x & (JSPLIT - 1);
    const int tmp  = blockIdx.x >> 2;
    const int gi   = tmp & ((NSEQ / IG) - 1);   // 0..255
    const int b    = tmp >> 8;
    const int tid  = threadIdx.x;
    const int wv = tid >> 6, lane = tid & 63;

    const int M  = M_g[b];
    const int i0 = gi * IG;
    if (i0 >= M) return;                 // block-uniform
    const int nI = min(IG, M - i0);

    const int Mq  = (M + JSPLIT - 1) >> 2;
    const int kLo = part * Mq;
    const int kHi = min(M, kLo + Mq);

    __shared__ int   s_irow[IG];
    __shared__ float s_ci[IG][3];
    __shared__ __align__(16) float s_rbf[IG][JCHUNK][20];  // 10 KB
    __shared__ __align__(16) float4 s_d4[IG][JCHUNK];      // 2 KB
    __shared__ int   s_jl[JCHUNK];
    __shared__ float s_red[4][IG][3];

    if (tid < IG) {
        if (tid < nI) {
            const int il  = jlist_g[b * NSEQ + i0 + tid];
            const int row = b * NSEQ + il;
            s_irow[tid] = row;
            s_ci[tid][0] = coords[(size_t)row * 3 + 0];
            s_ci[tid][1] = coords[(size_t)row * 3 + 1];
            s_ci[tid][2] = coords[(size_t)row * 3 + 2];
        } else {
            s_irow[tid] = b * NSEQ;      // dummy, in-range
            s_ci[tid][0] = 0.0f; s_ci[tid][1] = 0.0f; s_ci[tid][2] = 0.0f;
        }
    }
    __syncthreads();

    if (kLo >= kHi) {                    // empty j-slice: zero this part
        if (tid < nI * 3) {
            const int ii = tid / 3, c = tid % 3;
            cd_part[((size_t)s_irow[ii] * JSPLIT + part) * 3 + c] = 0.0f;
        }
        return;
    }

    float wprA[R], wprB[R];
    #pragma unroll
    for (int r = 0; r < R; ++r) {
        const float2 wv2 = ((const float2*)(w_pr + r * H))[lane];
        wprA[r] = wv2.x;
        wprB[r] = wv2.y;
    }
    const ushort2 u0v = ((const ushort2*)(pib_i + (size_t)s_irow[0] * H))[lane];
    const ushort2 u1v = ((const ushort2*)(pib_i + (size_t)s_irow[1] * H))[lane];
    const float pibx0 = bf2f(u0v.x), piby0 = bf2f(u0v.y);
    const float pibx1 = bf2f(u1v.x), piby1 = bf2f(u1v.y);
    const float2 wp22 = ((const float2*)w_p2)[lane];
    const float bp2 = b_p2[0];

    float cdx0 = 0.f, cdy0 = 0.f, cdz0 = 0.f, sdx0 = 0.f, sdy0 = 0.f, sdz0 = 0.f;
    float cdx1 = 0.f, cdy1 = 0.f, cdz1 = 0.f, sdx1 = 0.f, sdy1 = 0.f, sdz1 = 0.f;
    const float* pjb = pj_i + (size_t)b * NSEQ * H;
    const float gamma = 14.0625f;  // (15/4)^2

    for (int c0 = kLo; c0 < kHi; c0 += JCHUNK) {
        const int cn = min(JCHUNK, kHi - c0);
        __syncthreads();
        // staging: threads 0..127 handle (ii = tid>>6, kk = tid&63)
        {
            const int kk = tid & (JCHUNK - 1);
            const int ii = tid >> 6;
            if (ii < IG && kk < cn) {
                const int j = jlist_g[b * NSEQ + c0 + kk];
                if (ii == 0) s_jl[kk] = j;
                const float* cj = coords + (size_t)(b * NSEQ + j) * 3;
                const float dx = s_ci[ii][0] - cj[0];
                const float dy = s_ci[ii][1] - cj[1];
                const float dz = s_ci[ii][2] - cj[2];
                const float sq = dx * dx + dy * dy + dz * dz;
                const float dist = sqrtf(fmaxf(sq, 1e-12f));
                s_d4[ii][kk] = make_float4(dx, dy, dz, 0.0f);
                #pragma unroll
                for (int c = 0; c < 4; ++c) {
                    float4 q;
                    const float t0 = dist - (float)(4.0 * (4 * c + 0) / 15.0);
                    const float t1 = dist - (float)(4.0 * (4 * c + 1) / 15.0);
                    const float t2 = dist - (float)(4.0 * (4 * c + 2) / 15.0);
                    const float t3 = dist - (float)(4.0 * (4 * c + 3) / 15.0);
                    q.x = __expf(-gamma * t0 * t0);
                    q.y = __expf(-gamma * t1 * t1);
                    q.z = __expf(-gamma * t2 * t2);
                    q.w = __expf(-gamma * t3 * t3);
                    *(float4*)(&s_rbf[ii][kk][4 * c]) = q;
                }
            }
        }
        __syncthreads();
        // main loop: 2 pv loads in flight; each feeds IG=2 bodies
        for (int k = wv; k < cn; k += 8) {
            const int k2 = k + 4;
            const bool h2 = (k2 < cn);          // wave-uniform
            const int j0 = s_jl[k];
            const int j1 = s_jl[h2 ? k2 : k];
            const float2 pv0 = ((const float2*)(pjb + (size_t)j0 * H))[lane];
            const float2 pv1 = ((const float2*)(pjb + (size_t)j1 * H))[lane];

            pair_body(pv0.x, pv0.y, s_rbf[0][k], s_d4[0][k], pibx0, piby0,
                      wprA, wprB, wp22, cdx0, cdy0, cdz0, sdx0, sdy0, sdz0);
            pair_body(pv0.x, pv0.y, s_rbf[1][k], s_d4[1][k], pibx1, piby1,
                      wprA, wprB, wp22, cdx1, cdy1, cdz1, sdx1, sdy1, sdz1);
            if (h2) {
                pair_body(pv1.x, pv1.y, s_rbf[0][k2], s_d4[0][k2], pibx0, piby0,
                          wprA, wprB, wp22, cdx0, cdy0, cdz0, sdx0, sdy0, sdz0);
                pair_body(pv1.x, pv1.y, s_rbf[1][k2], s_d4[1][k2], pibx1, piby1,
                          wprA, wprB, wp22, cdx1, cdy1, cdz1, sdx1, sdy1, sdz1);
            }
        }
    }
    // per-i butterfly (once per block)
    #pragma unroll
    for (int off = 32; off; off >>= 1) {
        cdx0 += __shfl_xor(cdx0, off);
        cdy0 += __shfl_xor(cdy0, off);
        cdz0 += __shfl_xor(cdz0, off);
        cdx1 += __shfl_xor(cdx1, off);
        cdy1 += __shfl_xor(cdy1, off);
        cdz1 += __shfl_xor(cdz1, off);
    }
    if (lane == 0) {
        s_red[wv][0][0] = cdx0 + bp2 * sdx0;
        s_red[wv][0][1] = cdy0 + bp2 * sdy0;
        s_red[wv][0][2] = cdz0 + bp2 * sdz0;
        s_red[wv][1][0] = cdx1 + bp2 * sdx1;
        s_red[wv][1][1] = cdy1 + bp2 * sdy1;
        s_red[wv][1][2] = cdz1 + bp2 * sdz1;
    }
    __syncthreads();
    if (tid < nI * 3) {
        const int ii = tid / 3, c = tid % 3;
        cd_part[((size_t)s_irow[ii] * JSPLIT + part) * 3 + c] =
            s_red[0][ii][c] + s_red[1][ii][c] + s_red[2][ii][c] + s_red[3][ii][c];
    }
}

// ---------------- Kernel 3: finalize (sums JSPLIT parts; pad-gated) ----------------
__global__ __launch_bounds__(256) void finalize_kernel(
    const float* __restrict__ cd_part, const int* __restrict__ pad,
    float* __restrict__ out_coord)
{
    const int b = blockIdx.x;
    const int tid = threadIdx.x;
    __shared__ float r1[256], r2[256], r3[256], r4[256];
    float sx = 0.0f, sy = 0.0f, sz = 0.0f, cnt = 0.0f;
    for (int ii = tid; ii < NSEQ; ii += 256) {
        const int row = b * NSEQ + ii;
        if (pad[row] == 0) {
            float cx = 0.0f, cy = 0.0f, cz = 0.0f;
            #pragma unroll
            for (int q = 0; q < JSPLIT; ++q) {
                cx += cd_part[((size_t)row * JSPLIT + q) * 3 + 0];
                cy += cd_part[((size_t)row * JSPLIT + q) * 3 + 1];
                cz += cd_part[((size_t)row * JSPLIT + q) * 3 + 2];
            }
            sx += cx; sy += cy; sz += cz;
            cnt += 1.0f;
        }
    }
    r1[tid] = sx; r2[tid] = sy; r3[tid] = sz; r4[tid] = cnt;
    __syncthreads();
    for (int s = 128; s > 0; s >>= 1) {
        if (tid < s) {
            r1[tid] += r1[tid + s]; r2[tid] += r2[tid + s];
            r3[tid] += r3[tid + s]; r4[tid] += r4[tid + s];
        }
        __syncthreads();
    }
    const float denom = fmaxf(r4[0], 1.0f);
    const float inv_d = 1.0f / denom;
    const float mx = r1[0] * inv_d * inv_d;
    const float my = r2[0] * inv_d * inv_d;
    const float mz = r3[0] * inv_d * inv_d;
    for (int ii = tid; ii < NSEQ; ii += 256) {
        const int row = b * NSEQ + ii;
        if (pad[row] == 0) {
            float cx = 0.0f, cy = 0.0f, cz = 0.0f;
            #pragma unroll
            for (int q = 0; q < JSPLIT; ++q) {
                cx += cd_part[((size_t)row * JSPLIT + q) * 3 + 0];
                cy += cd_part[((size_t)row * JSPLIT + q) * 3 + 1];
                cz += cd_part[((size_t)row * JSPLIT + q) * 3 + 2];
            }
            out_coord[row * 3 + 0] = cx * inv_d - mx;
            out_coord[row * 3 + 1] = cy * inv_d - my;
            out_coord[row * 3 + 2] = cz * inv_d - mz;
        } else {
            out_coord[row * 3 + 0] = 0.0f;
            out_coord[row * 3 + 1] = 0.0f;
            out_coord[row * 3 + 2] = 0.0f;
        }
    }
}

extern "C" void kernel_launch(void* const* d_in, const int* in_sizes, int n_in,
                              void* d_out, int out_size, void* d_ws, size_t ws_size,
                              hipStream_t stream) {
    const float* trunk  = (const float*)d_in[0];
    const float* coords = (const float*)d_in[1];
    const int*   pad    = (const int*)d_in[2];
    const float* ln_g   = (const float*)d_in[3];
    const float* ln_b   = (const float*)d_in[4];
    const float* w_a1   = (const float*)d_in[5];
    const float* b_a1   = (const float*)d_in[6];
    const float* w_a2   = (const float*)d_in[7];
    const float* b_a2   = (const float*)d_in[8];
    const float* w_pi   = (const float*)d_in[9];
    const float* w_pj   = (const float*)d_in[10];
    const float* w_pr   = (const float*)d_in[11];
    const float* b_p1   = (const float*)d_in[12];
    const float* w_p2   = (const float*)d_in[13];
    const float* b_p2   = (const float*)d_in[14];

    float* out_atom  = (float*)d_out;                 // f32 [0:10240]
    float* out_coord = out_atom + (size_t)BN * AC;    // f32 [10240:16384]

    // ws: jlist[4*512] M[16] | cd_part[BN*JSPLIT*3] | pj f32[BN*H] | pib bf16[BN*H]
    int*   jlist_g = (int*)d_ws;
    int*   M_g     = jlist_g + 4 * NSEQ;
    float* cd_part = (float*)(M_g + 16);
    float* pj_buf  = cd_part + (size_t)BN * JSPLIT * 3;
    unsigned short* pib_buf = (unsigned short*)(pj_buf + (size_t)BN * H);

    batch_kernel<<<4, 256, 0, stream>>>(pad, jlist_g, M_g);
    row_kernel<<<BN / ROWG, 256, 0, stream>>>(trunk, pad, ln_g, ln_b, w_a1, b_a1,
                                              w_a2, b_a2, w_pi, w_pj, b_p1,
                                              out_atom, pj_buf, pib_buf);
    pair_kernel<<<4 * (NSEQ / IG) * JSPLIT, 256, 0, stream>>>(
        coords, w_pr, w_p2, b_p2, pj_buf, pib_buf, jlist_g, M_g, cd_part);
    finalize_kernel<<<4, 256, 0, stream>>>(cd_part, pad, out_coord);
}

// Round 33
// 68.974 us; speedup vs baseline: 1.1523x; 1.1048x over previous
//
#include <hip/hip_runtime.h>
#include <hip/hip_bf16.h>

#define BN 2048      // B*N
#define NSEQ 512
#define D 256
#define H 128
#define R 16
#define AC 5
#define CHUNK 128
#define ROWG 8
#define SPLIT 4

using bf16 = __hip_bfloat16;

__device__ __forceinline__ float fast_silu(float t) {
    const float e = __expf(-t);
    return t * __builtin_amdgcn_rcpf(1.0f + e);
}
__device__ __forceinline__ float bf2f(unsigned short u) {
    return __uint_as_float(((unsigned)u) << 16);
}

// ---------------- Kernel 0: per-batch valid-j compaction (R30, passes) ----------------
__global__ __launch_bounds__(256) void batch_kernel(
    const int* __restrict__ pad, int* __restrict__ jlist_g, int* __restrict__ M_g)
{
    const int b = blockIdx.x;
    const int tid = threadIdx.x;
    __shared__ int s_wcnt[8];
    __shared__ int s_wbase[8];
    const int wv = tid >> 6, lane = tid & 63;
    unsigned long long bm[2];
    #pragma unroll
    for (int cc = 0; cc < 2; ++cc) {
        const int j = cc * 256 + tid;
        const int ok = (pad[b * NSEQ + j] == 0);
        bm[cc] = __ballot(ok);
        if (lane == 0) s_wcnt[cc * 4 + wv] = __popcll(bm[cc]);
    }
    __syncthreads();
    if (tid == 0) {
        int acc = 0;
        #pragma unroll
        for (int q = 0; q < 8; ++q) { s_wbase[q] = acc; acc += s_wcnt[q]; }
        M_g[b] = acc;
    }
    __syncthreads();
    #pragma unroll
    for (int cc = 0; cc < 2; ++cc) {
        const int j = cc * 256 + tid;
        if (pad[b * NSEQ + j] == 0) {
            const int pos = s_wbase[cc * 4 + wv]
                          + __popcll(bm[cc] & ((1ull << lane) - 1ull));
            jlist_g[b * NSEQ + pos] = j;
        }
    }
}

// ---------------- Kernel 1: atom head + pj + pib, ROWG=8, 512 threads ----------------
// threads 0..255: a1 GEMM + a2 ; threads 256..383: pi ; threads 384..511: pj
__global__ __launch_bounds__(512) void row_kernel(
    const float* __restrict__ trunk, const int* __restrict__ pad,
    const float* __restrict__ ln_g, const float* __restrict__ ln_b,
    const float* __restrict__ w_a1, const float* __restrict__ b_a1,
    const float* __restrict__ w_a2, const float* __restrict__ b_a2,
    const float* __restrict__ w_pi, const float* __restrict__ w_pj,
    const float* __restrict__ b_p1,
    float* __restrict__ out_atom, float* __restrict__ pj_o,
    unsigned short* __restrict__ pib_o)
{
    const int row0 = blockIdx.x * ROWG;
    const int tid = threadIdx.x;   // 0..511
    const int wv = tid >> 6, lane = tid & 63;
    __shared__ __align__(16) float x_t[2][D][4];    // split layout: float4 = rows 0-3 / 4-7
    __shared__ __align__(16) float xn_t[2][D][4];
    __shared__ float y[ROWG][D];
    __shared__ float mu_s[ROWG], rs_s[ROWG];

    // stage 8 rows (512 threads: each loads 4 elements, coalesced within 256-groups)
    #pragma unroll
    for (int gg = 0; gg < 4; ++gg) {
        const int g = gg * 2 + (tid >> 8);
        const int e = tid & 255;
        x_t[g >> 2][e][g & 3] = trunk[(size_t)(row0 + g) * D + e];
    }
    __syncthreads();

    // LN stats: wave wv handles row wv (8 waves, 8 rows)
    {
        const int g = wv;
        float s = 0.0f, ss = 0.0f;
        #pragma unroll
        for (int e2 = lane; e2 < D; e2 += 64) {
            const float v = x_t[g >> 2][e2][g & 3];
            s += v; ss += v * v;
        }
        #pragma unroll
        for (int off = 32; off; off >>= 1) {
            s  += __shfl_xor(s, off);
            ss += __shfl_xor(ss, off);
        }
        if (lane == 0) {
            const float mu  = s * (1.0f / D);
            const float var = ss * (1.0f / D) - mu * mu;
            mu_s[g] = mu;
            rs_s[g] = rsqrtf(var + 1e-5f);
        }
    }
    __syncthreads();
    #pragma unroll
    for (int gg = 0; gg < 4; ++gg) {
        const int g = gg * 2 + (tid >> 8);
        const int e = tid & 255;
        xn_t[g >> 2][e][g & 3] =
            (x_t[g >> 2][e][g & 3] - mu_s[g]) * rs_s[g] * ln_g[e] + ln_b[e];
    }
    __syncthreads();

    if (tid < 256) {
        // a1: 8 accumulators, 1 weight load feeds 8 FMAs
        const float bb = b_a1[tid];
        float a0 = bb, a1v = bb, a2v = bb, a3 = bb, a4 = bb, a5 = bb, a6 = bb, a7 = bb;
        for (int d = 0; d < D; ++d) {
            const float w = w_a1[d * D + tid];
            const float4 lo = *(const float4*)xn_t[0][d];   // broadcast
            const float4 hi = *(const float4*)xn_t[1][d];
            a0  = fmaf(lo.x, w, a0);  a1v = fmaf(lo.y, w, a1v);
            a2v = fmaf(lo.z, w, a2v); a3  = fmaf(lo.w, w, a3);
            a4  = fmaf(hi.x, w, a4);  a5  = fmaf(hi.y, w, a5);
            a6  = fmaf(hi.z, w, a6);  a7  = fmaf(hi.w, w, a7);
        }
        y[0][tid] = a0  / (1.0f + expf(-a0));
        y[1][tid] = a1v / (1.0f + expf(-a1v));
        y[2][tid] = a2v / (1.0f + expf(-a2v));
        y[3][tid] = a3  / (1.0f + expf(-a3));
        y[4][tid] = a4  / (1.0f + expf(-a4));
        y[5][tid] = a5  / (1.0f + expf(-a5));
        y[6][tid] = a6  / (1.0f + expf(-a6));
        y[7][tid] = a7  / (1.0f + expf(-a7));
    } else if (tid < 384) {
        // pi for h = tid-256, 8 rows
        const int h = tid - 256;
        float p0 = 0.f, p1 = 0.f, p2 = 0.f, p3 = 0.f, p4 = 0.f, p5 = 0.f, p6 = 0.f, p7 = 0.f;
        for (int d = 0; d < D; ++d) {
            const float w = w_pi[d * H + h];
            const float4 lo = *(const float4*)x_t[0][d];
            const float4 hi = *(const float4*)x_t[1][d];
            p0 = fmaf(lo.x, w, p0); p1 = fmaf(lo.y, w, p1);
            p2 = fmaf(lo.z, w, p2); p3 = fmaf(lo.w, w, p3);
            p4 = fmaf(hi.x, w, p4); p5 = fmaf(hi.y, w, p5);
            p6 = fmaf(hi.z, w, p6); p7 = fmaf(hi.w, w, p7);
        }
        const float bb = b_p1[h];
        const float pv[ROWG] = {p0 + bb, p1 + bb, p2 + bb, p3 + bb,
                                p4 + bb, p5 + bb, p6 + bb, p7 + bb};
        #pragma unroll
        for (int g = 0; g < ROWG; ++g) {
            const bf16 pb = __float2bfloat16(pv[g]);
            pib_o[(size_t)(row0 + g) * H + h] = *(const unsigned short*)&pb;
        }
    } else {
        // pj for h = tid-384, 8 rows
        const int h = tid - 384;
        float p0 = 0.f, p1 = 0.f, p2 = 0.f, p3 = 0.f, p4 = 0.f, p5 = 0.f, p6 = 0.f, p7 = 0.f;
        for (int d = 0; d < D; ++d) {
            const float w = w_pj[d * H + h];
            const float4 lo = *(const float4*)x_t[0][d];
            const float4 hi = *(const float4*)x_t[1][d];
            p0 = fmaf(lo.x, w, p0); p1 = fmaf(lo.y, w, p1);
            p2 = fmaf(lo.z, w, p2); p3 = fmaf(lo.w, w, p3);
            p4 = fmaf(hi.x, w, p4); p5 = fmaf(hi.y, w, p5);
            p6 = fmaf(hi.z, w, p6); p7 = fmaf(hi.w, w, p7);
        }
        const float pv[ROWG] = {p0, p1, p2, p3, p4, p5, p6, p7};
        #pragma unroll
        for (int g = 0; g < ROWG; ++g)
            pj_o[(size_t)(row0 + g) * H + h] = pv[g];
    }
    __syncthreads();   // y fully written

    // a2: 40 threads (g = tid/AC, c = tid%AC)
    if (tid < ROWG * AC) {
        const int g = tid / AC, c = tid % AC;
        float a = b_a2[c];
        for (int d = 0; d < D; ++d) a = fmaf(y[g][d], w_a2[d * AC + c], a);
        out_atom[(row0 + g) * AC + c] = (pad[row0 + g] != 0) ? 0.0f : a;
    }
}

// per-pair inner body (R30, passes)
__device__ __forceinline__ void pair_body(
    const float pvx, const float pvy,
    const float* __restrict__ rbf_row, const float4 dk,
    const float pibx, const float piby,
    const float* wprA, const float* wprB, const float2 wp22,
    float& cdx, float& cdy, float& cdz,
    float& sdx, float& sdy, float& sdz)
{
    float t0a = pibx + pvx, t0b = 0.0f;
    float t1a = piby + pvy, t1b = 0.0f;
    #pragma unroll
    for (int r = 0; r < R; r += 2) {
        const float qa = rbf_row[r];
        const float qb = rbf_row[r + 1];
        t0a = fmaf(qa, wprA[r],     t0a);
        t0b = fmaf(qb, wprA[r + 1], t0b);
        t1a = fmaf(qa, wprB[r],     t1a);
        t1b = fmaf(qb, wprB[r + 1], t1b);
    }
    const float u0 = fast_silu(t0a + t0b);
    const float u1 = fast_silu(t1a + t1b);
    const float part = u0 * wp22.x + u1 * wp22.y;
    cdx = fmaf(part, dk.x, cdx);
    cdy = fmaf(part, dk.y, cdy);
    cdz = fmaf(part, dk.z, cdz);
    sdx += dk.x; sdy += dk.y; sdz += dk.z;
}

// ---------------- Kernel 2: pair head — SPLIT=4, 4-wide pv ILP (R30 exact, 48.4 µs) ----------------
__global__ __launch_bounds__(256) void pair_kernel(
    const float* __restrict__ coords, const int* __restrict__ pad,
    const float* __restrict__ w_pr, const float* __restrict__ w_p2,
    const float* __restrict__ b_p2,
    const float* __restrict__ pj_i, const unsigned short* __restrict__ pib_i,
    const int* __restrict__ jlist_g, const int* __restrict__ M_g,
    float* __restrict__ cd_part)   // [BN][SPLIT][3]
{
    const int row  = blockIdx.x >> 2;
    const int part_id = blockIdx.x & 3;
    const int b = row >> 9;
    const int tid = threadIdx.x;

    if (pad[row] != 0) {
        if (tid == 0) {
            cd_part[(row * SPLIT + part_id) * 3 + 0] = 0.0f;
            cd_part[(row * SPLIT + part_id) * 3 + 1] = 0.0f;
            cd_part[(row * SPLIT + part_id) * 3 + 2] = 0.0f;
        }
        return;
    }

    __shared__ __align__(16) float s_rbf[CHUNK][20];
    __shared__ __align__(16) float4 s_d4[CHUNK];
    __shared__ int   s_jl[CHUNK];
    __shared__ float rw1[4], rw2[4], rw3[4];

    const int wv = tid >> 6, lane = tid & 63;
    const int M = M_g[b];
    const int Mq  = (M + SPLIT - 1) / SPLIT;
    const int kLo = part_id * Mq;
    const int kHi = min(M, kLo + Mq);

    float wprA[R], wprB[R];
    #pragma unroll
    for (int r = 0; r < R; ++r) {
        const float2 wv2 = ((const float2*)(w_pr + r * H))[lane];
        wprA[r] = wv2.x;
        wprB[r] = wv2.y;
    }
    const ushort2 pibu = ((const ushort2*)(pib_i + (size_t)row * H))[lane];
    const float pibx = bf2f(pibu.x), piby = bf2f(pibu.y);
    const float2 wp22 = ((const float2*)w_p2)[lane];
    const float bp2 = b_p2[0];
    const float cix = coords[(size_t)row * 3 + 0];
    const float ciy = coords[(size_t)row * 3 + 1];
    const float ciz = coords[(size_t)row * 3 + 2];

    float cdx = 0.0f, cdy = 0.0f, cdz = 0.0f;
    float sdx = 0.0f, sdy = 0.0f, sdz = 0.0f;
    const float* pjb = pj_i + (size_t)b * NSEQ * H;
    const float gamma = 14.0625f;  // (15/4)^2

    for (int c0 = kLo; c0 < kHi; c0 += CHUNK) {
        const int cn = (kHi - c0 < CHUNK) ? (kHi - c0) : CHUNK;
        __syncthreads();
        if (tid < cn) {
            const int j = jlist_g[b * NSEQ + c0 + tid];
            s_jl[tid] = j;
            const float* cj = coords + (size_t)(b * NSEQ + j) * 3;
            const float dx = cix - cj[0];
            const float dy = ciy - cj[1];
            const float dz = ciz - cj[2];
            const float sq = dx * dx + dy * dy + dz * dz;
            const float dist = sqrtf(fmaxf(sq, 1e-12f));
            s_d4[tid] = make_float4(dx, dy, dz, 0.0f);
            #pragma unroll
            for (int c = 0; c < 4; ++c) {
                float4 q;
                const float t0 = dist - (float)(4.0 * (4 * c + 0) / 15.0);
                const float t1 = dist - (float)(4.0 * (4 * c + 1) / 15.0);
                const float t2 = dist - (float)(4.0 * (4 * c + 2) / 15.0);
                const float t3 = dist - (float)(4.0 * (4 * c + 3) / 15.0);
                q.x = __expf(-gamma * t0 * t0);
                q.y = __expf(-gamma * t1 * t1);
                q.z = __expf(-gamma * t2 * t2);
                q.w = __expf(-gamma * t3 * t3);
                *(float4*)(&s_rbf[tid][4 * c]) = q;
            }
        }
        __syncthreads();
        // 4-wide ILP: 4 pv loads in flight per wave-iteration
        for (int k = wv; k < cn; k += 16) {
            const int k1 = k + 4, k2 = k + 8, k3 = k + 12;
            const bool h1 = (k1 < cn), h2 = (k2 < cn), h3 = (k3 < cn);
            const int j0 = s_jl[k];
            const int j1 = s_jl[h1 ? k1 : k];
            const int j2 = s_jl[h2 ? k2 : k];
            const int j3 = s_jl[h3 ? k3 : k];
            const float2 pv0 = ((const float2*)(pjb + (size_t)j0 * H))[lane];
            const float2 pv1 = ((const float2*)(pjb + (size_t)j1 * H))[lane];
            const float2 pv2 = ((const float2*)(pjb + (size_t)j2 * H))[lane];
            const float2 pv3 = ((const float2*)(pjb + (size_t)j3 * H))[lane];

            pair_body(pv0.x, pv0.y, s_rbf[k], s_d4[k], pibx, piby,
                      wprA, wprB, wp22, cdx, cdy, cdz, sdx, sdy, sdz);
            if (h1) pair_body(pv1.x, pv1.y, s_rbf[k1], s_d4[k1], pibx, piby,
                              wprA, wprB, wp22, cdx, cdy, cdz, sdx, sdy, sdz);
            if (h2) pair_body(pv2.x, pv2.y, s_rbf[k2], s_d4[k2], pibx, piby,
                              wprA, wprB, wp22, cdx, cdy, cdz, sdx, sdy, sdz);
            if (h3) pair_body(pv3.x, pv3.y, s_rbf[k3], s_d4[k3], pibx, piby,
                              wprA, wprB, wp22, cdx, cdy, cdz, sdx, sdy, sdz);
        }
    }
    #pragma unroll
    for (int off = 32; off; off >>= 1) {
        cdx += __shfl_xor(cdx, off);
        cdy += __shfl_xor(cdy, off);
        cdz += __shfl_xor(cdz, off);
    }
    if (lane == 0) {
        rw1[wv] = cdx + bp2 * sdx;
        rw2[wv] = cdy + bp2 * sdy;
        rw3[wv] = cdz + bp2 * sdz;
    }
    __syncthreads();
    if (tid == 0) {
        cd_part[(row * SPLIT + part_id) * 3 + 0] = rw1[0] + rw1[1] + rw1[2] + rw1[3];
        cd_part[(row * SPLIT + part_id) * 3 + 1] = rw2[0] + rw2[1] + rw2[2] + rw2[3];
        cd_part[(row * SPLIT + part_id) * 3 + 2] = rw3[0] + rw3[1] + rw3[2] + rw3[3];
    }
}

// ---------------- Kernel 3: finalize (R30 exact, passes) ----------------
__global__ __launch_bounds__(256) void finalize_kernel(
    const float* __restrict__ cd_part, const int* __restrict__ pad,
    float* __restrict__ out_coord)
{
    const int b = blockIdx.x;
    const int tid = threadIdx.x;
    __shared__ float r1[256], r2[256], r3[256], r4[256];
    float sx = 0.0f, sy = 0.0f, sz = 0.0f, cnt = 0.0f;
    for (int ii = tid; ii < NSEQ; ii += 256) {
        const int row = b * NSEQ + ii;
        if (pad[row] == 0) {
            float cx = 0.0f, cy = 0.0f, cz = 0.0f;
            #pragma unroll
            for (int q = 0; q < SPLIT; ++q) {
                cx += cd_part[(row * SPLIT + q) * 3 + 0];
                cy += cd_part[(row * SPLIT + q) * 3 + 1];
                cz += cd_part[(row * SPLIT + q) * 3 + 2];
            }
            sx += cx; sy += cy; sz += cz;
            cnt += 1.0f;
        }
    }
    r1[tid] = sx; r2[tid] = sy; r3[tid] = sz; r4[tid] = cnt;
    __syncthreads();
    for (int s = 128; s > 0; s >>= 1) {
        if (tid < s) {
            r1[tid] += r1[tid + s]; r2[tid] += r2[tid + s];
            r3[tid] += r3[tid + s]; r4[tid] += r4[tid + s];
        }
        __syncthreads();
    }
    const float denom = fmaxf(r4[0], 1.0f);
    const float inv_d = 1.0f / denom;
    const float mx = r1[0] * inv_d * inv_d;
    const float my = r2[0] * inv_d * inv_d;
    const float mz = r3[0] * inv_d * inv_d;
    for (int ii = tid; ii < NSEQ; ii += 256) {
        const int row = b * NSEQ + ii;
        const bool v = (pad[row] == 0);
        float cx = 0.0f, cy = 0.0f, cz = 0.0f;
        #pragma unroll
        for (int q = 0; q < SPLIT; ++q) {
            cx += cd_part[(row * SPLIT + q) * 3 + 0];
            cy += cd_part[(row * SPLIT + q) * 3 + 1];
            cz += cd_part[(row * SPLIT + q) * 3 + 2];
        }
        out_coord[row * 3 + 0] = v ? cx * inv_d - mx : 0.0f;
        out_coord[row * 3 + 1] = v ? cy * inv_d - my : 0.0f;
        out_coord[row * 3 + 2] = v ? cz * inv_d - mz : 0.0f;
    }
}

extern "C" void kernel_launch(void* const* d_in, const int* in_sizes, int n_in,
                              void* d_out, int out_size, void* d_ws, size_t ws_size,
                              hipStream_t stream) {
    const float* trunk  = (const float*)d_in[0];
    const float* coords = (const float*)d_in[1];
    const int*   pad    = (const int*)d_in[2];
    const float* ln_g   = (const float*)d_in[3];
    const float* ln_b   = (const float*)d_in[4];
    const float* w_a1   = (const float*)d_in[5];
    const float* b_a1   = (const float*)d_in[6];
    const float* w_a2   = (const float*)d_in[7];
    const float* b_a2   = (const float*)d_in[8];
    const float* w_pi   = (const float*)d_in[9];
    const float* w_pj   = (const float*)d_in[10];
    const float* w_pr   = (const float*)d_in[11];
    const float* b_p1   = (const float*)d_in[12];
    const float* w_p2   = (const float*)d_in[13];
    const float* b_p2   = (const float*)d_in[14];

    float* out_atom  = (float*)d_out;                 // f32 [0:10240]
    float* out_coord = out_atom + (size_t)BN * AC;    // f32 [10240:16384]

    // ws: jlist[4*512] M[16] | cd_part[BN*SPLIT*3] | pj f32[BN*H] | pib bf16[BN*H]
    int*   jlist_g = (int*)d_ws;
    int*   M_g     = jlist_g + 4 * NSEQ;
    float* cd_part = (float*)(M_g + 16);
    float* pj_buf  = cd_part + (size_t)BN * SPLIT * 3;
    unsigned short* pib_buf = (unsigned short*)(pj_buf + (size_t)BN * H);

    batch_kernel<<<4, 256, 0, stream>>>(pad, jlist_g, M_g);
    row_kernel<<<BN / ROWG, 512, 0, stream>>>(trunk, pad, ln_g, ln_b, w_a1, b_a1,
                                              w_a2, b_a2, w_pi, w_pj, b_p1,
                                              out_atom, pj_buf, pib_buf);
    pair_kernel<<<BN * SPLIT, 256, 0, stream>>>(coords, pad, w_pr, w_p2, b_p2,
                                                pj_buf, pib_buf, jlist_g, M_g, cd_part);
    finalize_kernel<<<4, 256, 0, stream>>>(cd_part, pad, out_coord);
}

// Round 34
// 68.253 us; speedup vs baseline: 1.1645x; 1.0106x over previous
//
#include <hip/hip_runtime.h>
#include <hip/hip_bf16.h>

#define BN 2048      // B*N
#define NSEQ 512
#define D 256
#define H 128
#define R 16
#define AC 5
#define CHUNK 128
#define ROWG 8
#define SPLIT 4

using bf16 = __hip_bfloat16;

__device__ __forceinline__ float fast_silu(float t) {
    const float e = __expf(-t);
    return t * __builtin_amdgcn_rcpf(1.0f + e);
}
__device__ __forceinline__ float bf2f(unsigned short u) {
    return __uint_as_float(((unsigned)u) << 16);
}

// ---------------- Kernel 0: per-batch valid-j compaction (passes) ----------------
__global__ __launch_bounds__(256) void batch_kernel(
    const int* __restrict__ pad, int* __restrict__ jlist_g, int* __restrict__ M_g)
{
    const int b = blockIdx.x;
    const int tid = threadIdx.x;
    __shared__ int s_wcnt[8];
    __shared__ int s_wbase[8];
    const int wv = tid >> 6, lane = tid & 63;
    unsigned long long bm[2];
    #pragma unroll
    for (int cc = 0; cc < 2; ++cc) {
        const int j = cc * 256 + tid;
        const int ok = (pad[b * NSEQ + j] == 0);
        bm[cc] = __ballot(ok);
        if (lane == 0) s_wcnt[cc * 4 + wv] = __popcll(bm[cc]);
    }
    __syncthreads();
    if (tid == 0) {
        int acc = 0;
        #pragma unroll
        for (int q = 0; q < 8; ++q) { s_wbase[q] = acc; acc += s_wcnt[q]; }
        M_g[b] = acc;
    }
    __syncthreads();
    #pragma unroll
    for (int cc = 0; cc < 2; ++cc) {
        const int j = cc * 256 + tid;
        if (pad[b * NSEQ + j] == 0) {
            const int pos = s_wbase[cc * 4 + wv]
                          + __popcll(bm[cc] & ((1ull << lane) - 1ull));
            jlist_g[b * NSEQ + pos] = j;
        }
    }
}

// ---------------- Kernel 1: atom head + pj + pib, ROWG=8, 512 threads (R33, passes) ----------------
__global__ __launch_bounds__(512) void row_kernel(
    const float* __restrict__ trunk, const int* __restrict__ pad,
    const float* __restrict__ ln_g, const float* __restrict__ ln_b,
    const float* __restrict__ w_a1, const float* __restrict__ b_a1,
    const float* __restrict__ w_a2, const float* __restrict__ b_a2,
    const float* __restrict__ w_pi, const float* __restrict__ w_pj,
    const float* __restrict__ b_p1,
    float* __restrict__ out_atom, float* __restrict__ pj_o,
    unsigned short* __restrict__ pib_o)
{
    const int row0 = blockIdx.x * ROWG;
    const int tid = threadIdx.x;   // 0..511
    const int wv = tid >> 6, lane = tid & 63;
    __shared__ __align__(16) float x_t[2][D][4];
    __shared__ __align__(16) float xn_t[2][D][4];
    __shared__ float y[ROWG][D];
    __shared__ float mu_s[ROWG], rs_s[ROWG];

    #pragma unroll
    for (int gg = 0; gg < 4; ++gg) {
        const int g = gg * 2 + (tid >> 8);
        const int e = tid & 255;
        x_t[g >> 2][e][g & 3] = trunk[(size_t)(row0 + g) * D + e];
    }
    __syncthreads();

    {
        const int g = wv;
        float s = 0.0f, ss = 0.0f;
        #pragma unroll
        for (int e2 = lane; e2 < D; e2 += 64) {
            const float v = x_t[g >> 2][e2][g & 3];
            s += v; ss += v * v;
        }
        #pragma unroll
        for (int off = 32; off; off >>= 1) {
            s  += __shfl_xor(s, off);
            ss += __shfl_xor(ss, off);
        }
        if (lane == 0) {
            const float mu  = s * (1.0f / D);
            const float var = ss * (1.0f / D) - mu * mu;
            mu_s[g] = mu;
            rs_s[g] = rsqrtf(var + 1e-5f);
        }
    }
    __syncthreads();
    #pragma unroll
    for (int gg = 0; gg < 4; ++gg) {
        const int g = gg * 2 + (tid >> 8);
        const int e = tid & 255;
        xn_t[g >> 2][e][g & 3] =
            (x_t[g >> 2][e][g & 3] - mu_s[g]) * rs_s[g] * ln_g[e] + ln_b[e];
    }
    __syncthreads();

    if (tid < 256) {
        const float bb = b_a1[tid];
        float a0 = bb, a1v = bb, a2v = bb, a3 = bb, a4 = bb, a5 = bb, a6 = bb, a7 = bb;
        for (int d = 0; d < D; ++d) {
            const float w = w_a1[d * D + tid];
            const float4 lo = *(const float4*)xn_t[0][d];
            const float4 hi = *(const float4*)xn_t[1][d];
            a0  = fmaf(lo.x, w, a0);  a1v = fmaf(lo.y, w, a1v);
            a2v = fmaf(lo.z, w, a2v); a3  = fmaf(lo.w, w, a3);
            a4  = fmaf(hi.x, w, a4);  a5  = fmaf(hi.y, w, a5);
            a6  = fmaf(hi.z, w, a6);  a7  = fmaf(hi.w, w, a7);
        }
        y[0][tid] = a0  / (1.0f + expf(-a0));
        y[1][tid] = a1v / (1.0f + expf(-a1v));
        y[2][tid] = a2v / (1.0f + expf(-a2v));
        y[3][tid] = a3  / (1.0f + expf(-a3));
        y[4][tid] = a4  / (1.0f + expf(-a4));
        y[5][tid] = a5  / (1.0f + expf(-a5));
        y[6][tid] = a6  / (1.0f + expf(-a6));
        y[7][tid] = a7  / (1.0f + expf(-a7));
    } else if (tid < 384) {
        const int h = tid - 256;
        float p0 = 0.f, p1 = 0.f, p2 = 0.f, p3 = 0.f, p4 = 0.f, p5 = 0.f, p6 = 0.f, p7 = 0.f;
        for (int d = 0; d < D; ++d) {
            const float w = w_pi[d * H + h];
            const float4 lo = *(const float4*)x_t[0][d];
            const float4 hi = *(const float4*)x_t[1][d];
            p0 = fmaf(lo.x, w, p0); p1 = fmaf(lo.y, w, p1);
            p2 = fmaf(lo.z, w, p2); p3 = fmaf(lo.w, w, p3);
            p4 = fmaf(hi.x, w, p4); p5 = fmaf(hi.y, w, p5);
            p6 = fmaf(hi.z, w, p6); p7 = fmaf(hi.w, w, p7);
        }
        const float bb = b_p1[h];
        const float pv[ROWG] = {p0 + bb, p1 + bb, p2 + bb, p3 + bb,
                                p4 + bb, p5 + bb, p6 + bb, p7 + bb};
        #pragma unroll
        for (int g = 0; g < ROWG; ++g) {
            const bf16 pb = __float2bfloat16(pv[g]);
            pib_o[(size_t)(row0 + g) * H + h] = *(const unsigned short*)&pb;
        }
    } else {
        const int h = tid - 384;
        float p0 = 0.f, p1 = 0.f, p2 = 0.f, p3 = 0.f, p4 = 0.f, p5 = 0.f, p6 = 0.f, p7 = 0.f;
        for (int d = 0; d < D; ++d) {
            const float w = w_pj[d * H + h];
            const float4 lo = *(const float4*)x_t[0][d];
            const float4 hi = *(const float4*)x_t[1][d];
            p0 = fmaf(lo.x, w, p0); p1 = fmaf(lo.y, w, p1);
            p2 = fmaf(lo.z, w, p2); p3 = fmaf(lo.w, w, p3);
            p4 = fmaf(hi.x, w, p4); p5 = fmaf(hi.y, w, p5);
            p6 = fmaf(hi.z, w, p6); p7 = fmaf(hi.w, w, p7);
        }
        const float pv[ROWG] = {p0, p1, p2, p3, p4, p5, p6, p7};
        #pragma unroll
        for (int g = 0; g < ROWG; ++g)
            pj_o[(size_t)(row0 + g) * H + h] = pv[g];
    }
    __syncthreads();

    if (tid < ROWG * AC) {
        const int g = tid / AC, c = tid % AC;
        float a = b_a2[c];
        for (int d = 0; d < D; ++d) a = fmaf(y[g][d], w_a2[d * AC + c], a);
        out_atom[(row0 + g) * AC + c] = (pad[row0 + g] != 0) ? 0.0f : a;
    }
}

// per-pair inner body (passes)
__device__ __forceinline__ void pair_body(
    const float pvx, const float pvy,
    const float* __restrict__ rbf_row, const float4 dk,
    const float pibx, const float piby,
    const float* wprA, const float* wprB, const float2 wp22,
    float& cdx, float& cdy, float& cdz,
    float& sdx, float& sdy, float& sdz)
{
    float t0a = pibx + pvx, t0b = 0.0f;
    float t1a = piby + pvy, t1b = 0.0f;
    #pragma unroll
    for (int r = 0; r < R; r += 2) {
        const float qa = rbf_row[r];
        const float qb = rbf_row[r + 1];
        t0a = fmaf(qa, wprA[r],     t0a);
        t0b = fmaf(qb, wprA[r + 1], t0b);
        t1a = fmaf(qa, wprB[r],     t1a);
        t1b = fmaf(qb, wprB[r + 1], t1b);
    }
    const float u0 = fast_silu(t0a + t0b);
    const float u1 = fast_silu(t1a + t1b);
    const float part = u0 * wp22.x + u1 * wp22.y;
    cdx = fmaf(part, dk.x, cdx);
    cdy = fmaf(part, dk.y, cdy);
    cdz = fmaf(part, dk.z, cdz);
    sdx += dk.x; sdy += dk.y; sdz += dk.z;
}

// ---------------- Kernel 2: pair head — SPLIT=4, cross-iteration pipelined 4-wide pv ----------------
__global__ __launch_bounds__(256) void pair_kernel(
    const float* __restrict__ coords, const int* __restrict__ pad,
    const float* __restrict__ w_pr, const float* __restrict__ w_p2,
    const float* __restrict__ b_p2,
    const float* __restrict__ pj_i, const unsigned short* __restrict__ pib_i,
    const int* __restrict__ jlist_g, const int* __restrict__ M_g,
    float* __restrict__ cd_part)   // [BN][SPLIT][3]
{
    const int row  = blockIdx.x >> 2;
    const int part_id = blockIdx.x & 3;
    const int b = row >> 9;
    const int tid = threadIdx.x;

    if (pad[row] != 0) {
        if (tid == 0) {
            cd_part[(row * SPLIT + part_id) * 3 + 0] = 0.0f;
            cd_part[(row * SPLIT + part_id) * 3 + 1] = 0.0f;
            cd_part[(row * SPLIT + part_id) * 3 + 2] = 0.0f;
        }
        return;
    }

    __shared__ __align__(16) float s_rbf[CHUNK][20];
    __shared__ __align__(16) float4 s_d4[CHUNK];
    __shared__ int   s_jl[CHUNK];
    __shared__ float rw1[4], rw2[4], rw3[4];

    const int wv = tid >> 6, lane = tid & 63;
    const int M = M_g[b];
    const int Mq  = (M + SPLIT - 1) / SPLIT;
    const int kLo = part_id * Mq;
    const int kHi = min(M, kLo + Mq);

    float wprA[R], wprB[R];
    #pragma unroll
    for (int r = 0; r < R; ++r) {
        const float2 wv2 = ((const float2*)(w_pr + r * H))[lane];
        wprA[r] = wv2.x;
        wprB[r] = wv2.y;
    }
    const ushort2 pibu = ((const ushort2*)(pib_i + (size_t)row * H))[lane];
    const float pibx = bf2f(pibu.x), piby = bf2f(pibu.y);
    const float2 wp22 = ((const float2*)w_p2)[lane];
    const float bp2 = b_p2[0];
    const float cix = coords[(size_t)row * 3 + 0];
    const float ciy = coords[(size_t)row * 3 + 1];
    const float ciz = coords[(size_t)row * 3 + 2];

    float cdx = 0.0f, cdy = 0.0f, cdz = 0.0f;
    float sdx = 0.0f, sdy = 0.0f, sdz = 0.0f;
    const float* pjb = pj_i + (size_t)b * NSEQ * H;
    const float gamma = 14.0625f;  // (15/4)^2

    for (int c0 = kLo; c0 < kHi; c0 += CHUNK) {
        const int cn = (kHi - c0 < CHUNK) ? (kHi - c0) : CHUNK;
        __syncthreads();
        if (tid < cn) {
            const int j = jlist_g[b * NSEQ + c0 + tid];
            s_jl[tid] = j;
            const float* cj = coords + (size_t)(b * NSEQ + j) * 3;
            const float dx = cix - cj[0];
            const float dy = ciy - cj[1];
            const float dz = ciz - cj[2];
            const float sq = dx * dx + dy * dy + dz * dz;
            const float dist = sqrtf(fmaxf(sq, 1e-12f));
            s_d4[tid] = make_float4(dx, dy, dz, 0.0f);
            #pragma unroll
            for (int c = 0; c < 4; ++c) {
                float4 q;
                const float t0 = dist - (float)(4.0 * (4 * c + 0) / 15.0);
                const float t1 = dist - (float)(4.0 * (4 * c + 1) / 15.0);
                const float t2 = dist - (float)(4.0 * (4 * c + 2) / 15.0);
                const float t3 = dist - (float)(4.0 * (4 * c + 3) / 15.0);
                q.x = __expf(-gamma * t0 * t0);
                q.y = __expf(-gamma * t1 * t1);
                q.z = __expf(-gamma * t2 * t2);
                q.w = __expf(-gamma * t3 * t3);
                *(float4*)(&s_rbf[tid][4 * c]) = q;
            }
        }
        __syncthreads();

        // ---- software-pipelined main loop: next iteration's loads issued before current compute ----
        const int cl = cn - 1;
        int k = wv;
        // prologue: loads for first iteration (clamped addresses; safe even if wv >= cn)
        float2 pv0 = ((const float2*)(pjb + (size_t)s_jl[min(k,      cl)] * H))[lane];
        float2 pv1 = ((const float2*)(pjb + (size_t)s_jl[min(k + 4,  cl)] * H))[lane];
        float2 pv2 = ((const float2*)(pjb + (size_t)s_jl[min(k + 8,  cl)] * H))[lane];
        float2 pv3 = ((const float2*)(pjb + (size_t)s_jl[min(k + 12, cl)] * H))[lane];
        for (; k < cn; k += 16) {
            // issue next iteration's loads (clamped; wasted on last iter, harmless)
            const int kn = k + 16;
            const float2 nv0 = ((const float2*)(pjb + (size_t)s_jl[min(kn,      cl)] * H))[lane];
            const float2 nv1 = ((const float2*)(pjb + (size_t)s_jl[min(kn + 4,  cl)] * H))[lane];
            const float2 nv2 = ((const float2*)(pjb + (size_t)s_jl[min(kn + 8,  cl)] * H))[lane];
            const float2 nv3 = ((const float2*)(pjb + (size_t)s_jl[min(kn + 12, cl)] * H))[lane];

            const int k1 = k + 4, k2 = k + 8, k3 = k + 12;
            pair_body(pv0.x, pv0.y, s_rbf[k], s_d4[k], pibx, piby,
                      wprA, wprB, wp22, cdx, cdy, cdz, sdx, sdy, sdz);
            if (k1 < cn) pair_body(pv1.x, pv1.y, s_rbf[k1], s_d4[k1], pibx, piby,
                                   wprA, wprB, wp22, cdx, cdy, cdz, sdx, sdy, sdz);
            if (k2 < cn) pair_body(pv2.x, pv2.y, s_rbf[k2], s_d4[k2], pibx, piby,
                                   wprA, wprB, wp22, cdx, cdy, cdz, sdx, sdy, sdz);
            if (k3 < cn) pair_body(pv3.x, pv3.y, s_rbf[k3], s_d4[k3], pibx, piby,
                                   wprA, wprB, wp22, cdx, cdy, cdz, sdx, sdy, sdz);
            pv0 = nv0; pv1 = nv1; pv2 = nv2; pv3 = nv3;
        }
    }
    #pragma unroll
    for (int off = 32; off; off >>= 1) {
        cdx += __shfl_xor(cdx, off);
        cdy += __shfl_xor(cdy, off);
        cdz += __shfl_xor(cdz, off);
    }
    if (lane == 0) {
        rw1[wv] = cdx + bp2 * sdx;
        rw2[wv] = cdy + bp2 * sdy;
        rw3[wv] = cdz + bp2 * sdz;
    }
    __syncthreads();
    if (tid == 0) {
        cd_part[(row * SPLIT + part_id) * 3 + 0] = rw1[0] + rw1[1] + rw1[2] + rw1[3];
        cd_part[(row * SPLIT + part_id) * 3 + 1] = rw2[0] + rw2[1] + rw2[2] + rw2[3];
        cd_part[(row * SPLIT + part_id) * 3 + 2] = rw3[0] + rw3[1] + rw3[2] + rw3[3];
    }
}

// ---------------- Kernel 3: finalize (passes) ----------------
__global__ __launch_bounds__(256) void finalize_kernel(
    const float* __restrict__ cd_part, const int* __restrict__ pad,
    float* __restrict__ out_coord)
{
    const int b = blockIdx.x;
    const int tid = threadIdx.x;
    __shared__ float r1[256], r2[256], r3[256], r4[256];
    float sx = 0.0f, sy = 0.0f, sz = 0.0f, cnt = 0.0f;
    for (int ii = tid; ii < NSEQ; ii += 256) {
        const int row = b * NSEQ + ii;
        if (pad[row] == 0) {
            float cx = 0.0f, cy = 0.0f, cz = 0.0f;
            #pragma unroll
            for (int q = 0; q < SPLIT; ++q) {
                cx += cd_part[(row * SPLIT + q) * 3 + 0];
                cy += cd_part[(row * SPLIT + q) * 3 + 1];
                cz += cd_part[(row * SPLIT + q) * 3 + 2];
            }
            sx += cx; sy += cy; sz += cz;
            cnt += 1.0f;
        }
    }
    r1[tid] = sx; r2[tid] = sy; r3[tid] = sz; r4[tid] = cnt;
    __syncthreads();
    for (int s = 128; s > 0; s >>= 1) {
        if (tid < s) {
            r1[tid] += r1[tid + s]; r2[tid] += r2[tid + s];
            r3[tid] += r3[tid + s]; r4[tid] += r4[tid + s];
        }
        __syncthreads();
    }
    const float denom = fmaxf(r4[0], 1.0f);
    const float inv_d = 1.0f / denom;
    const float mx = r1[0] * inv_d * inv_d;
    const float my = r2[0] * inv_d * inv_d;
    const float mz = r3[0] * inv_d * inv_d;
    for (int ii = tid; ii < NSEQ; ii += 256) {
        const int row = b * NSEQ + ii;
        const bool v = (pad[row] == 0);
        float cx = 0.0f, cy = 0.0f, cz = 0.0f;
        #pragma unroll
        for (int q = 0; q < SPLIT; ++q) {
            cx += cd_part[(row * SPLIT + q) * 3 + 0];
            cy += cd_part[(row * SPLIT + q) * 3 + 1];
            cz += cd_part[(row * SPLIT + q) * 3 + 2];
        }
        out_coord[row * 3 + 0] = v ? cx * inv_d - mx : 0.0f;
        out_coord[row * 3 + 1] = v ? cy * inv_d - my : 0.0f;
        out_coord[row * 3 + 2] = v ? cz * inv_d - mz : 0.0f;
    }
}

extern "C" void kernel_launch(void* const* d_in, const int* in_sizes, int n_in,
                              void* d_out, int out_size, void* d_ws, size_t ws_size,
                              hipStream_t stream) {
    const float* trunk  = (const float*)d_in[0];
    const float* coords = (const float*)d_in[1];
    const int*   pad    = (const int*)d_in[2];
    const float* ln_g   = (const float*)d_in[3];
    const float* ln_b   = (const float*)d_in[4];
    const float* w_a1   = (const float*)d_in[5];
    const float* b_a1   = (const float*)d_in[6];
    const float* w_a2   = (const float*)d_in[7];
    const float* b_a2   = (const float*)d_in[8];
    const float* w_pi   = (const float*)d_in[9];
    const float* w_pj   = (const float*)d_in[10];
    const float* w_pr   = (const float*)d_in[11];
    const float* b_p1   = (const float*)d_in[12];
    const float* w_p2   = (const float*)d_in[13];
    const float* b_p2   = (const float*)d_in[14];

    float* out_atom  = (float*)d_out;                 // f32 [0:10240]
    float* out_coord = out_atom + (size_t)BN * AC;    // f32 [10240:16384]

    // ws: jlist[4*512] M[16] | cd_part[BN*SPLIT*3] | pj f32[BN*H] | pib bf16[BN*H]
    int*   jlist_g = (int*)d_ws;
    int*   M_g     = jlist_g + 4 * NSEQ;
    float* cd_part = (float*)(M_g + 16);
    float* pj_buf  = cd_part + (size_t)BN * SPLIT * 3;
    unsigned short* pib_buf = (unsigned short*)(pj_buf + (size_t)BN * H);

    batch_kernel<<<4, 256, 0, stream>>>(pad, jlist_g, M_g);
    row_kernel<<<BN / ROWG, 512, 0, stream>>>(trunk, pad, ln_g, ln_b, w_a1, b_a1,
                                              w_a2, b_a2, w_pi, w_pj, b_p1,
                                              out_atom, pj_buf, pib_buf);
    pair_kernel<<<BN * SPLIT, 256, 0, stream>>>(coords, pad, w_pr, w_p2, b_p2,
                                                pj_buf, pib_buf, jlist_g, M_g, cd_part);
    finalize_kernel<<<4, 256, 0, stream>>>(cd_part, pad, out_coord);
}

// Round 35
// 66.198 us; speedup vs baseline: 1.2007x; 1.0310x over previous
//
#include <hip/hip_runtime.h>
#include <hip/hip_bf16.h>

#define BN 2048      // B*N
#define NSEQ 512
#define D 256
#define H 128
#define R 16
#define AC 5
#define CHUNK 128
#define ROWG 8
#define SPLIT 4

using bf16 = __hip_bfloat16;

__device__ __forceinline__ float fast_silu(float t) {
    const float e = __expf(-t);
    return t * __builtin_amdgcn_rcpf(1.0f + e);
}
__device__ __forceinline__ float bf2f(unsigned short u) {
    return __uint_as_float(((unsigned)u) << 16);
}
__device__ __forceinline__ unsigned short f2bu(float v) {
    const bf16 pb = __float2bfloat16(v);
    return *(const unsigned short*)&pb;
}

// ---------------- Kernel 0: per-batch valid-j compaction + coord sum ----------------
__global__ __launch_bounds__(256) void batch_kernel(
    const int* __restrict__ pad, const float* __restrict__ coords,
    int* __restrict__ jlist_g, int* __restrict__ M_g, float* __restrict__ csum_g)
{
    const int b = blockIdx.x;
    const int tid = threadIdx.x;
    __shared__ int s_wcnt[8];
    __shared__ int s_wbase[8];
    __shared__ float r1[256], r2[256], r3[256];
    const int wv = tid >> 6, lane = tid & 63;
    unsigned long long bm[2];
    float sx = 0.0f, sy = 0.0f, sz = 0.0f;
    #pragma unroll
    for (int cc = 0; cc < 2; ++cc) {
        const int j = cc * 256 + tid;
        const int ok = (pad[b * NSEQ + j] == 0);
        bm[cc] = __ballot(ok);
        if (lane == 0) s_wcnt[cc * 4 + wv] = __popcll(bm[cc]);
        if (ok) {
            sx += coords[(size_t)(b * NSEQ + j) * 3 + 0];
            sy += coords[(size_t)(b * NSEQ + j) * 3 + 1];
            sz += coords[(size_t)(b * NSEQ + j) * 3 + 2];
        }
    }
    r1[tid] = sx; r2[tid] = sy; r3[tid] = sz;
    __syncthreads();
    for (int s = 128; s > 0; s >>= 1) {
        if (tid < s) { r1[tid] += r1[tid + s]; r2[tid] += r2[tid + s]; r3[tid] += r3[tid + s]; }
        __syncthreads();
    }
    if (tid == 0) {
        int acc = 0;
        #pragma unroll
        for (int q = 0; q < 8; ++q) { s_wbase[q] = acc; acc += s_wcnt[q]; }
        M_g[b] = acc;
        csum_g[b * 3 + 0] = r1[0];
        csum_g[b * 3 + 1] = r2[0];
        csum_g[b * 3 + 2] = r3[0];
    }
    __syncthreads();
    #pragma unroll
    for (int cc = 0; cc < 2; ++cc) {
        const int j = cc * 256 + tid;
        if (pad[b * NSEQ + j] == 0) {
            const int pos = s_wbase[cc * 4 + wv]
                          + __popcll(bm[cc] & ((1ull << lane) - 1ull));
            jlist_g[b * NSEQ + pos] = j;
        }
    }
}

// ---------------- Kernel 1: atom head + pj(bf16) + pib(bf16), ROWG=8, 512 threads ----------------
__global__ __launch_bounds__(512) void row_kernel(
    const float* __restrict__ trunk, const int* __restrict__ pad,
    const float* __restrict__ ln_g, const float* __restrict__ ln_b,
    const float* __restrict__ w_a1, const float* __restrict__ b_a1,
    const float* __restrict__ w_a2, const float* __restrict__ b_a2,
    const float* __restrict__ w_pi, const float* __restrict__ w_pj,
    const float* __restrict__ b_p1,
    float* __restrict__ out_atom, unsigned short* __restrict__ pj_o,
    unsigned short* __restrict__ pib_o)
{
    const int row0 = blockIdx.x * ROWG;
    const int tid = threadIdx.x;   // 0..511
    const int wv = tid >> 6, lane = tid & 63;
    __shared__ __align__(16) float x_t[2][D][4];
    __shared__ __align__(16) float xn_t[2][D][4];
    __shared__ float y[ROWG][D];
    __shared__ float mu_s[ROWG], rs_s[ROWG];

    #pragma unroll
    for (int gg = 0; gg < 4; ++gg) {
        const int g = gg * 2 + (tid >> 8);
        const int e = tid & 255;
        x_t[g >> 2][e][g & 3] = trunk[(size_t)(row0 + g) * D + e];
    }
    __syncthreads();

    {
        const int g = wv;
        float s = 0.0f, ss = 0.0f;
        #pragma unroll
        for (int e2 = lane; e2 < D; e2 += 64) {
            const float v = x_t[g >> 2][e2][g & 3];
            s += v; ss += v * v;
        }
        #pragma unroll
        for (int off = 32; off; off >>= 1) {
            s  += __shfl_xor(s, off);
            ss += __shfl_xor(ss, off);
        }
        if (lane == 0) {
            const float mu  = s * (1.0f / D);
            const float var = ss * (1.0f / D) - mu * mu;
            mu_s[g] = mu;
            rs_s[g] = rsqrtf(var + 1e-5f);
        }
    }
    __syncthreads();
    #pragma unroll
    for (int gg = 0; gg < 4; ++gg) {
        const int g = gg * 2 + (tid >> 8);
        const int e = tid & 255;
        xn_t[g >> 2][e][g & 3] =
            (x_t[g >> 2][e][g & 3] - mu_s[g]) * rs_s[g] * ln_g[e] + ln_b[e];
    }
    __syncthreads();

    if (tid < 256) {
        const float bb = b_a1[tid];
        float a0 = bb, a1v = bb, a2v = bb, a3 = bb, a4 = bb, a5 = bb, a6 = bb, a7 = bb;
        for (int d = 0; d < D; ++d) {
            const float w = w_a1[d * D + tid];
            const float4 lo = *(const float4*)xn_t[0][d];
            const float4 hi = *(const float4*)xn_t[1][d];
            a0  = fmaf(lo.x, w, a0);  a1v = fmaf(lo.y, w, a1v);
            a2v = fmaf(lo.z, w, a2v); a3  = fmaf(lo.w, w, a3);
            a4  = fmaf(hi.x, w, a4);  a5  = fmaf(hi.y, w, a5);
            a6  = fmaf(hi.z, w, a6);  a7  = fmaf(hi.w, w, a7);
        }
        y[0][tid] = a0  / (1.0f + expf(-a0));
        y[1][tid] = a1v / (1.0f + expf(-a1v));
        y[2][tid] = a2v / (1.0f + expf(-a2v));
        y[3][tid] = a3  / (1.0f + expf(-a3));
        y[4][tid] = a4  / (1.0f + expf(-a4));
        y[5][tid] = a5  / (1.0f + expf(-a5));
        y[6][tid] = a6  / (1.0f + expf(-a6));
        y[7][tid] = a7  / (1.0f + expf(-a7));
    } else if (tid < 384) {
        const int h = tid - 256;
        float p0 = 0.f, p1 = 0.f, p2 = 0.f, p3 = 0.f, p4 = 0.f, p5 = 0.f, p6 = 0.f, p7 = 0.f;
        for (int d = 0; d < D; ++d) {
            const float w = w_pi[d * H + h];
            const float4 lo = *(const float4*)x_t[0][d];
            const float4 hi = *(const float4*)x_t[1][d];
            p0 = fmaf(lo.x, w, p0); p1 = fmaf(lo.y, w, p1);
            p2 = fmaf(lo.z, w, p2); p3 = fmaf(lo.w, w, p3);
            p4 = fmaf(hi.x, w, p4); p5 = fmaf(hi.y, w, p5);
            p6 = fmaf(hi.z, w, p6); p7 = fmaf(hi.w, w, p7);
        }
        const float bb = b_p1[h];
        const float pv[ROWG] = {p0 + bb, p1 + bb, p2 + bb, p3 + bb,
                                p4 + bb, p5 + bb, p6 + bb, p7 + bb};
        #pragma unroll
        for (int g = 0; g < ROWG; ++g)
            pib_o[(size_t)(row0 + g) * H + h] = f2bu(pv[g]);
    } else {
        const int h = tid - 384;
        float p0 = 0.f, p1 = 0.f, p2 = 0.f, p3 = 0.f, p4 = 0.f, p5 = 0.f, p6 = 0.f, p7 = 0.f;
        for (int d = 0; d < D; ++d) {
            const float w = w_pj[d * H + h];
            const float4 lo = *(const float4*)x_t[0][d];
            const float4 hi = *(const float4*)x_t[1][d];
            p0 = fmaf(lo.x, w, p0); p1 = fmaf(lo.y, w, p1);
            p2 = fmaf(lo.z, w, p2); p3 = fmaf(lo.w, w, p3);
            p4 = fmaf(hi.x, w, p4); p5 = fmaf(hi.y, w, p5);
            p6 = fmaf(hi.z, w, p6); p7 = fmaf(hi.w, w, p7);
        }
        const float pv[ROWG] = {p0, p1, p2, p3, p4, p5, p6, p7};
        #pragma unroll
        for (int g = 0; g < ROWG; ++g)
            pj_o[(size_t)(row0 + g) * H + h] = f2bu(pv[g]);
    }
    __syncthreads();

    if (tid < ROWG * AC) {
        const int g = tid / AC, c = tid % AC;
        float a = b_a2[c];
        for (int d = 0; d < D; ++d) a = fmaf(y[g][d], w_a2[d * AC + c], a);
        out_atom[(row0 + g) * AC + c] = (pad[row0 + g] != 0) ? 0.0f : a;
    }
}

// per-pair inner body (no sd accumulation — bp2 term handled in finalize)
__device__ __forceinline__ void pair_body(
    const float pvx, const float pvy,
    const float* __restrict__ rbf_row, const float4 dk,
    const float pibx, const float piby,
    const float* wprA, const float* wprB, const float2 wp22,
    float& cdx, float& cdy, float& cdz)
{
    float t0a = pibx + pvx, t0b = 0.0f;
    float t1a = piby + pvy, t1b = 0.0f;
    #pragma unroll
    for (int r = 0; r < R; r += 2) {
        const float qa = rbf_row[r];
        const float qb = rbf_row[r + 1];
        t0a = fmaf(qa, wprA[r],     t0a);
        t0b = fmaf(qb, wprA[r + 1], t0b);
        t1a = fmaf(qa, wprB[r],     t1a);
        t1b = fmaf(qb, wprB[r + 1], t1b);
    }
    const float u0 = fast_silu(t0a + t0b);
    const float u1 = fast_silu(t1a + t1b);
    const float part = u0 * wp22.x + u1 * wp22.y;
    cdx = fmaf(part, dk.x, cdx);
    cdy = fmaf(part, dk.y, cdy);
    cdz = fmaf(part, dk.z, cdz);
}

// ---------------- Kernel 2: pair head — SPLIT=4, pipelined 4-wide bf16 pv ----------------
__global__ __launch_bounds__(256) void pair_kernel(
    const float* __restrict__ coords, const int* __restrict__ pad,
    const float* __restrict__ w_pr, const float* __restrict__ w_p2,
    const unsigned short* __restrict__ pj_i, const unsigned short* __restrict__ pib_i,
    const int* __restrict__ jlist_g, const int* __restrict__ M_g,
    float* __restrict__ cd_part)   // [BN][SPLIT][3]
{
    const int row  = blockIdx.x >> 2;
    const int part_id = blockIdx.x & 3;
    const int b = row >> 9;
    const int tid = threadIdx.x;

    if (pad[row] != 0) {
        if (tid == 0) {
            cd_part[(row * SPLIT + part_id) * 3 + 0] = 0.0f;
            cd_part[(row * SPLIT + part_id) * 3 + 1] = 0.0f;
            cd_part[(row * SPLIT + part_id) * 3 + 2] = 0.0f;
        }
        return;
    }

    __shared__ __align__(16) float s_rbf[CHUNK][20];
    __shared__ __align__(16) float4 s_d4[CHUNK];
    __shared__ int   s_jl[CHUNK];
    __shared__ float rw1[4], rw2[4], rw3[4];

    const int wv = tid >> 6, lane = tid & 63;
    const int M = M_g[b];
    const int Mq  = (M + SPLIT - 1) / SPLIT;
    const int kLo = part_id * Mq;
    const int kHi = min(M, kLo + Mq);

    float wprA[R], wprB[R];
    #pragma unroll
    for (int r = 0; r < R; ++r) {
        const float2 wv2 = ((const float2*)(w_pr + r * H))[lane];
        wprA[r] = wv2.x;
        wprB[r] = wv2.y;
    }
    const ushort2 pibu = ((const ushort2*)(pib_i + (size_t)row * H))[lane];
    const float pibx = bf2f(pibu.x), piby = bf2f(pibu.y);
    const float2 wp22 = ((const float2*)w_p2)[lane];
    const float cix = coords[(size_t)row * 3 + 0];
    const float ciy = coords[(size_t)row * 3 + 1];
    const float ciz = coords[(size_t)row * 3 + 2];

    float cdx = 0.0f, cdy = 0.0f, cdz = 0.0f;
    const unsigned short* pjb = pj_i + (size_t)b * NSEQ * H;
    const float gamma = 14.0625f;  // (15/4)^2

    for (int c0 = kLo; c0 < kHi; c0 += CHUNK) {
        const int cn = (kHi - c0 < CHUNK) ? (kHi - c0) : CHUNK;
        __syncthreads();
        if (tid < cn) {
            const int j = jlist_g[b * NSEQ + c0 + tid];
            s_jl[tid] = j;
            const float* cj = coords + (size_t)(b * NSEQ + j) * 3;
            const float dx = cix - cj[0];
            const float dy = ciy - cj[1];
            const float dz = ciz - cj[2];
            const float sq = dx * dx + dy * dy + dz * dz;
            const float dist = sqrtf(fmaxf(sq, 1e-12f));
            s_d4[tid] = make_float4(dx, dy, dz, 0.0f);
            #pragma unroll
            for (int c = 0; c < 4; ++c) {
                float4 q;
                const float t0 = dist - (float)(4.0 * (4 * c + 0) / 15.0);
                const float t1 = dist - (float)(4.0 * (4 * c + 1) / 15.0);
                const float t2 = dist - (float)(4.0 * (4 * c + 2) / 15.0);
                const float t3 = dist - (float)(4.0 * (4 * c + 3) / 15.0);
                q.x = __expf(-gamma * t0 * t0);
                q.y = __expf(-gamma * t1 * t1);
                q.z = __expf(-gamma * t2 * t2);
                q.w = __expf(-gamma * t3 * t3);
                *(float4*)(&s_rbf[tid][4 * c]) = q;
            }
        }
        __syncthreads();

        const int cl = cn - 1;
        int k = wv;
        ushort2 pv0 = ((const ushort2*)(pjb + (size_t)s_jl[min(k,      cl)] * H))[lane];
        ushort2 pv1 = ((const ushort2*)(pjb + (size_t)s_jl[min(k + 4,  cl)] * H))[lane];
        ushort2 pv2 = ((const ushort2*)(pjb + (size_t)s_jl[min(k + 8,  cl)] * H))[lane];
        ushort2 pv3 = ((const ushort2*)(pjb + (size_t)s_jl[min(k + 12, cl)] * H))[lane];
        for (; k < cn; k += 16) {
            const int kn = k + 16;
            const ushort2 nv0 = ((const ushort2*)(pjb + (size_t)s_jl[min(kn,      cl)] * H))[lane];
            const ushort2 nv1 = ((const ushort2*)(pjb + (size_t)s_jl[min(kn + 4,  cl)] * H))[lane];
            const ushort2 nv2 = ((const ushort2*)(pjb + (size_t)s_jl[min(kn + 8,  cl)] * H))[lane];
            const ushort2 nv3 = ((const ushort2*)(pjb + (size_t)s_jl[min(kn + 12, cl)] * H))[lane];

            const int k1 = k + 4, k2 = k + 8, k3 = k + 12;
            pair_body(bf2f(pv0.x), bf2f(pv0.y), s_rbf[k], s_d4[k], pibx, piby,
                      wprA, wprB, wp22, cdx, cdy, cdz);
            if (k1 < cn) pair_body(bf2f(pv1.x), bf2f(pv1.y), s_rbf[k1], s_d4[k1], pibx, piby,
                                   wprA, wprB, wp22, cdx, cdy, cdz);
            if (k2 < cn) pair_body(bf2f(pv2.x), bf2f(pv2.y), s_rbf[k2], s_d4[k2], pibx, piby,
                                   wprA, wprB, wp22, cdx, cdy, cdz);
            if (k3 < cn) pair_body(bf2f(pv3.x), bf2f(pv3.y), s_rbf[k3], s_d4[k3], pibx, piby,
                                   wprA, wprB, wp22, cdx, cdy, cdz);
            pv0 = nv0; pv1 = nv1; pv2 = nv2; pv3 = nv3;
        }
    }
    #pragma unroll
    for (int off = 32; off; off >>= 1) {
        cdx += __shfl_xor(cdx, off);
        cdy += __shfl_xor(cdy, off);
        cdz += __shfl_xor(cdz, off);
    }
    if (lane == 0) { rw1[wv] = cdx; rw2[wv] = cdy; rw3[wv] = cdz; }
    __syncthreads();
    if (tid == 0) {
        cd_part[(row * SPLIT + part_id) * 3 + 0] = rw1[0] + rw1[1] + rw1[2] + rw1[3];
        cd_part[(row * SPLIT + part_id) * 3 + 1] = rw2[0] + rw2[1] + rw2[2] + rw2[3];
        cd_part[(row * SPLIT + part_id) * 3 + 2] = rw3[0] + rw3[1] + rw3[2] + rw3[3];
    }
}

// ---------------- Kernel 3: finalize — adds closed-form bp2 term, CoM, /denom ----------------
__global__ __launch_bounds__(256) void finalize_kernel(
    const float* __restrict__ cd_part, const int* __restrict__ pad,
    const float* __restrict__ coords, const int* __restrict__ M_g,
    const float* __restrict__ csum_g, const float* __restrict__ b_p2,
    float* __restrict__ out_coord)
{
    const int b = blockIdx.x;
    const int tid = threadIdx.x;
    __shared__ float r1[256], r2[256], r3[256];
    const float bp2 = b_p2[0];
    const float Mf  = (float)M_g[b];
    const float csx = csum_g[b * 3 + 0];
    const float csy = csum_g[b * 3 + 1];
    const float csz = csum_g[b * 3 + 2];

    float sx = 0.0f, sy = 0.0f, sz = 0.0f;
    for (int ii = tid; ii < NSEQ; ii += 256) {
        const int row = b * NSEQ + ii;
        if (pad[row] == 0) {
            float cx = bp2 * fmaf(Mf, coords[(size_t)row * 3 + 0], -csx);
            float cy = bp2 * fmaf(Mf, coords[(size_t)row * 3 + 1], -csy);
            float cz = bp2 * fmaf(Mf, coords[(size_t)row * 3 + 2], -csz);
            #pragma unroll
            for (int q = 0; q < SPLIT; ++q) {
                cx += cd_part[(row * SPLIT + q) * 3 + 0];
                cy += cd_part[(row * SPLIT + q) * 3 + 1];
                cz += cd_part[(row * SPLIT + q) * 3 + 2];
            }
            sx += cx; sy += cy; sz += cz;
        }
    }
    r1[tid] = sx; r2[tid] = sy; r3[tid] = sz;
    __syncthreads();
    for (int s = 128; s > 0; s >>= 1) {
        if (tid < s) { r1[tid] += r1[tid + s]; r2[tid] += r2[tid + s]; r3[tid] += r3[tid + s]; }
        __syncthreads();
    }
    const float denom = fmaxf(Mf, 1.0f);
    const float inv_d = 1.0f / denom;
    const float mx = r1[0] * inv_d * inv_d;
    const float my = r2[0] * inv_d * inv_d;
    const float mz = r3[0] * inv_d * inv_d;
    for (int ii = tid; ii < NSEQ; ii += 256) {
        const int row = b * NSEQ + ii;
        if (pad[row] == 0) {
            float cx = bp2 * fmaf(Mf, coords[(size_t)row * 3 + 0], -csx);
            float cy = bp2 * fmaf(Mf, coords[(size_t)row * 3 + 1], -csy);
            float cz = bp2 * fmaf(Mf, coords[(size_t)row * 3 + 2], -csz);
            #pragma unroll
            for (int q = 0; q < SPLIT; ++q) {
                cx += cd_part[(row * SPLIT + q) * 3 + 0];
                cy += cd_part[(row * SPLIT + q) * 3 + 1];
                cz += cd_part[(row * SPLIT + q) * 3 + 2];
            }
            out_coord[row * 3 + 0] = cx * inv_d - mx;
            out_coord[row * 3 + 1] = cy * inv_d - my;
            out_coord[row * 3 + 2] = cz * inv_d - mz;
        } else {
            out_coord[row * 3 + 0] = 0.0f;
            out_coord[row * 3 + 1] = 0.0f;
            out_coord[row * 3 + 2] = 0.0f;
        }
    }
}

extern "C" void kernel_launch(void* const* d_in, const int* in_sizes, int n_in,
                              void* d_out, int out_size, void* d_ws, size_t ws_size,
                              hipStream_t stream) {
    const float* trunk  = (const float*)d_in[0];
    const float* coords = (const float*)d_in[1];
    const int*   pad    = (const int*)d_in[2];
    const float* ln_g   = (const float*)d_in[3];
    const float* ln_b   = (const float*)d_in[4];
    const float* w_a1   = (const float*)d_in[5];
    const float* b_a1   = (const float*)d_in[6];
    const float* w_a2   = (const float*)d_in[7];
    const float* b_a2   = (const float*)d_in[8];
    const float* w_pi   = (const float*)d_in[9];
    const float* w_pj   = (const float*)d_in[10];
    const float* w_pr   = (const float*)d_in[11];
    const float* b_p1   = (const float*)d_in[12];
    const float* w_p2   = (const float*)d_in[13];
    const float* b_p2   = (const float*)d_in[14];

    float* out_atom  = (float*)d_out;                 // f32 [0:10240]
    float* out_coord = out_atom + (size_t)BN * AC;    // f32 [10240:16384]

    // ws: jlist[4*512] M[16] csum[16] | cd_part[BN*SPLIT*3] | pj bf16[BN*H] | pib bf16[BN*H]
    int*   jlist_g = (int*)d_ws;
    int*   M_g     = jlist_g + 4 * NSEQ;
    float* csum_g  = (float*)(M_g + 16);
    float* cd_part = csum_g + 16;
    unsigned short* pj_buf  = (unsigned short*)(cd_part + (size_t)BN * SPLIT * 3);
    unsigned short* pib_buf = pj_buf + (size_t)BN * H;

    batch_kernel<<<4, 256, 0, stream>>>(pad, coords, jlist_g, M_g, csum_g);
    row_kernel<<<BN / ROWG, 512, 0, stream>>>(trunk, pad, ln_g, ln_b, w_a1, b_a1,
                                              w_a2, b_a2, w_pi, w_pj, b_p1,
                                              out_atom, pj_buf, pib_buf);
    pair_kernel<<<BN * SPLIT, 256, 0, stream>>>(coords, pad, w_pr, w_p2,
                                                pj_buf, pib_buf, jlist_g, M_g, cd_part);
    finalize_kernel<<<4, 256, 0, stream>>>(cd_part, pad, coords, M_g, csum_g,
                                           b_p2, out_coord);
}